// Round 13
// baseline (742.749 us; speedup 1.0000x reference)
//
#include <hip/hip_runtime.h>

// GConvGRU (ChebConv K=3, GRU with H=0) on MI355X.
// H=0 => out = (1 - sigmoid(Cz + bhz)) * tanh(Ch + bhh); Cz/Ch share the
// Chebyshev basis Tx0=x, Tx1=P x, Tx2=2 P Tx1 - x, P = -D^{-1/2} A D^{-1/2}.
// Factorization: P v = -dinv .* (A_w^T (dinv .* v)), so records store raw w.
//
// R8-R12: propacc pinned at ~198us under every MLP/cache intervention ->
// the random y[src] gather is the immovable cost. This round ELIMINATES it:
// two-pass counting sort (by src-bucket, then by dst-bucket). Pass B's
// chunked scatter preserves order, so dst-bucket records arrive grouped by
// src-bucket -> a wave's gathers fall in an ~8KB y window (L1-local).

static constexpr int BLK = 256;
static constexpr int BLK_SS = 512;      // sort block
static constexpr int BLK_ACC = 512;
static constexpr int NBC_MAX = 512;     // max coarse buckets (n <= 2^19)
static constexpr int BSHIFT = 10;       // 1024 nodes/bucket
static constexpr int BSIZE = 1024;
static constexpr int SCH = 4096;        // records per sort chunk

__device__ __forceinline__ void atomAddF(float* p, float v) {
    unsafeAtomicAdd(p, v);
}

// ---------------- utility ----------------

__global__ void k_zero_ints(int* __restrict__ p, int n)
{
    int i = blockIdx.x * blockDim.x + threadIdx.x;
    if (i < n) p[i] = 0;
}

__global__ void k_zero_f4(float4* __restrict__ p, long long n4)
{
    long long i = (long long)blockIdx.x * blockDim.x + threadIdx.x;
    long long stride = (long long)gridDim.x * blockDim.x;
    for (; i < n4; i += stride) p[i] = make_float4(0.f, 0.f, 0.f, 0.f);
}

// ---------------- histogram + scan ----------------

__global__ void k_hist(const int* __restrict__ srcp, const int* __restrict__ dstp,
                       int* __restrict__ histS, int* __restrict__ histD,
                       long long ne, int NB)
{
    __shared__ int lS[NBC_MAX];
    __shared__ int lD[NBC_MAX];
    for (int b = threadIdx.x; b < NB; b += blockDim.x) { lS[b] = 0; lD[b] = 0; }
    __syncthreads();

    const long long ng = (ne + 3) >> 2;
    const long long stride = (long long)gridDim.x * blockDim.x;
    for (long long g = (long long)blockIdx.x * blockDim.x + threadIdx.x; g < ng; g += stride) {
        const long long e = g << 2;
        if (e + 3 < ne) {
            int4 s4 = *(const int4*)(srcp + e);
            int4 d4 = *(const int4*)(dstp + e);
            atomicAdd(&lS[s4.x >> BSHIFT], 1); atomicAdd(&lS[s4.y >> BSHIFT], 1);
            atomicAdd(&lS[s4.z >> BSHIFT], 1); atomicAdd(&lS[s4.w >> BSHIFT], 1);
            atomicAdd(&lD[d4.x >> BSHIFT], 1); atomicAdd(&lD[d4.y >> BSHIFT], 1);
            atomicAdd(&lD[d4.z >> BSHIFT], 1); atomicAdd(&lD[d4.w >> BSHIFT], 1);
        } else {
            for (long long q = e; q < ne; ++q) {
                atomicAdd(&lS[srcp[q] >> BSHIFT], 1);
                atomicAdd(&lD[dstp[q] >> BSHIFT], 1);
            }
        }
    }
    __syncthreads();
    for (int b = threadIdx.x; b < NB; b += blockDim.x) {
        if (lS[b]) atomicAdd(&histS[b], lS[b]);
        if (lD[b]) atomicAdd(&histD[b], lD[b]);
    }
}

// Exclusive scan: block 0 does S, block 1 does D. NB <= 512, BLK=256.
__global__ void k_scan(const int* __restrict__ histS, int* __restrict__ baseS, int* __restrict__ curS,
                       const int* __restrict__ histD, int* __restrict__ baseD, int* __restrict__ curD,
                       int NB)
{
    const int* hist = (blockIdx.x == 0) ? histS : histD;
    int* base = (blockIdx.x == 0) ? baseS : baseD;
    int* cur  = (blockIdx.x == 0) ? curS  : curD;

    __shared__ int part[BLK];
    int t = threadIdx.x;
    int v0 = (2 * t     < NB) ? hist[2 * t]     : 0;
    int v1 = (2 * t + 1 < NB) ? hist[2 * t + 1] : 0;
    part[t] = v0 + v1;
    __syncthreads();
    for (int off = 1; off < BLK; off <<= 1) {
        int val = (t >= off) ? part[t - off] : 0;
        __syncthreads();
        part[t] += val;
        __syncthreads();
    }
    int run = (t == 0) ? 0 : part[t - 1];
    if (2 * t < NB)     { base[2 * t] = run;          cur[2 * t] = run; }
    if (2 * t + 1 < NB) { base[2 * t + 1] = run + v0; cur[2 * t + 1] = run + v0; }
}

// ---------------- pass A: sort raw edges by src-bucket ----------------
// recA = { dst(19b) | srcLocal(10b)<<19 , w_full } (w=0 for self-loops)
__global__ __launch_bounds__(BLK_SS)
void k_sortA(const int* __restrict__ srcp, const int* __restrict__ dstp,
             const float* __restrict__ w, int* __restrict__ curS,
             uint2* __restrict__ recA, long long ne, int NB, int NCH)
{
    __shared__ uint2 stage[SCH];            // 32 KB
    __shared__ unsigned short slotbkt[SCH]; // 8 KB
    __shared__ int loff[NBC_MAX];
    __shared__ int gdelta[NBC_MAX];
    __shared__ int stmp[BLK_SS];

    const int orig = blockIdx.x;
    const int xcd = orig & 7, idx = orig >> 3;
    const int q8 = NCH >> 3, r8 = NCH & 7;
    const int chunk = (xcd < r8 ? xcd * (q8 + 1) : r8 * (q8 + 1) + (xcd - r8) * q8) + idx;

    const long long cs = (long long)chunk * SCH;
    if (cs >= ne) return;
    const int cnt = (int)(((cs + SCH) < ne) ? SCH : (ne - cs));
    const int t = threadIdx.x;

    for (int b = t; b < NB; b += BLK_SS) loff[b] = 0;
    __syncthreads();

    // pass 1: count by src-bucket
    for (int i = t * 4; i < cnt; i += BLK_SS * 4) {
        if (i + 3 < cnt) {
            int4 k4 = *(const int4*)(srcp + cs + i);
            atomicAdd(&loff[k4.x >> BSHIFT], 1); atomicAdd(&loff[k4.y >> BSHIFT], 1);
            atomicAdd(&loff[k4.z >> BSHIFT], 1); atomicAdd(&loff[k4.w >> BSHIFT], 1);
        } else {
            for (int q = i; q < cnt; ++q)
                atomicAdd(&loff[srcp[cs + q] >> BSHIFT], 1);
        }
    }
    __syncthreads();

    // scan + reserve
    int v = (t < NB) ? loff[t] : 0;
    stmp[t] = v;
    __syncthreads();
    for (int off = 1; off < BLK_SS; off <<= 1) {
        int val = (t >= off) ? stmp[t - off] : 0;
        __syncthreads();
        stmp[t] += val;
        __syncthreads();
    }
    int excl = stmp[t] - v;
    if (t < NB) {
        int g = (v > 0) ? atomicAdd(&curS[t], v) : 0;
        loff[t] = excl;
        gdelta[t] = g - excl;
    }
    __syncthreads();

    // pass 2: place
    for (int i = t * 4; i < cnt; i += BLK_SS * 4) {
        if (i + 3 < cnt) {
            int4 s4 = *(const int4*)(srcp + cs + i);
            int4 d4 = *(const int4*)(dstp + cs + i);
            float4 w4 = *(const float4*)(w + cs + i);
            int ss[4] = {s4.x, s4.y, s4.z, s4.w};
            int dd[4] = {d4.x, d4.y, d4.z, d4.w};
            float wv[4] = {w4.x, w4.y, w4.z, w4.w};
#pragma unroll
            for (int j = 0; j < 4; ++j) {
                float we = (ss[j] == dd[j]) ? 0.0f : wv[j];
                int b = ss[j] >> BSHIFT;
                int pos = atomicAdd(&loff[b], 1);
                stage[pos] = make_uint2(
                    (unsigned)dd[j] | ((unsigned)(ss[j] & (BSIZE - 1)) << 19),
                    __float_as_uint(we));
                slotbkt[pos] = (unsigned short)b;
            }
        } else {
            for (int q = i; q < cnt; ++q) {
                int s = srcp[cs + q], d = dstp[cs + q];
                float we = (s == d) ? 0.0f : w[cs + q];
                int b = s >> BSHIFT;
                int pos = atomicAdd(&loff[b], 1);
                stage[pos] = make_uint2(
                    (unsigned)d | ((unsigned)(s & (BSIZE - 1)) << 19),
                    __float_as_uint(we));
                slotbkt[pos] = (unsigned short)b;
            }
        }
    }
    __syncthreads();

    // pass 3: flush
    for (int i = t; i < cnt; i += BLK_SS) {
        int b = slotbkt[i];
        recA[(long long)(i + gdelta[b])] = stage[i];
    }
}

// ---------------- pass B: re-sort recA by dst-bucket ----------------
// recB = { srcFull(19b) | dstLocal(10b)<<19 , w } ; srcFull reconstructed
// from record position via baseS (records grouped by src-bucket in recA).
__global__ __launch_bounds__(BLK_SS)
void k_sortB(const uint2* __restrict__ recA, const int* __restrict__ baseS,
             int* __restrict__ curD, uint2* __restrict__ recB,
             long long ne, int NB, int NCH)
{
    __shared__ uint2 stage[SCH];            // 32 KB
    __shared__ unsigned short slotbkt[SCH]; // 8 KB
    __shared__ int loff[NBC_MAX];
    __shared__ int gdelta[NBC_MAX];
    __shared__ int stmp[BLK_SS];
    __shared__ int lbaseS[NBC_MAX];

    const int orig = blockIdx.x;
    const int xcd = orig & 7, idx = orig >> 3;
    const int q8 = NCH >> 3, r8 = NCH & 7;
    const int chunk = (xcd < r8 ? xcd * (q8 + 1) : r8 * (q8 + 1) + (xcd - r8) * q8) + idx;

    const long long cs = (long long)chunk * SCH;
    if (cs >= ne) return;
    const int cnt = (int)(((cs + SCH) < ne) ? SCH : (ne - cs));
    const int t = threadIdx.x;

    for (int b = t; b < NB; b += BLK_SS) { loff[b] = 0; lbaseS[b] = baseS[b]; }
    __syncthreads();

    // pass 1: count by dst-bucket
    for (int i = t * 2; i < cnt; i += BLK_SS * 2) {
        if (i + 1 < cnt) {
            uint4 two = *(const uint4*)(recA + cs + i);
            atomicAdd(&loff[(two.x & 0x7FFFFu) >> BSHIFT], 1);
            atomicAdd(&loff[(two.z & 0x7FFFFu) >> BSHIFT], 1);
        } else {
            uint2 one = recA[cs + i];
            atomicAdd(&loff[(one.x & 0x7FFFFu) >> BSHIFT], 1);
        }
    }
    __syncthreads();

    // scan + reserve
    int v = (t < NB) ? loff[t] : 0;
    stmp[t] = v;
    __syncthreads();
    for (int off = 1; off < BLK_SS; off <<= 1) {
        int val = (t >= off) ? stmp[t - off] : 0;
        __syncthreads();
        stmp[t] += val;
        __syncthreads();
    }
    int excl = stmp[t] - v;
    if (t < NB) {
        int g = (v > 0) ? atomicAdd(&curD[t], v) : 0;
        loff[t] = excl;
        gdelta[t] = g - excl;
    }
    __syncthreads();

    // pass 2: place; srcFull = (srcBucket(p) << 10) | srcLocal
    for (int i = t; i < cnt; i += BLK_SS) {
        uint2 rec = recA[cs + i];
        int p = (int)0;  // position-based src bucket via bsearch on lbaseS
        {
            long long gp = cs + i;
            int lo = 0, hi = NB;
            while (hi - lo > 1) {
                int mid = (lo + hi) >> 1;
                if ((long long)lbaseS[mid] <= gp) lo = mid; else hi = mid;
            }
            p = lo;
        }
        unsigned dstF = rec.x & 0x7FFFFu;
        unsigned srcL = (rec.x >> 19) & (BSIZE - 1u);
        unsigned srcF = ((unsigned)p << BSHIFT) | srcL;
        int b = (int)(dstF >> BSHIFT);
        int pos = atomicAdd(&loff[b], 1);
        stage[pos] = make_uint2(srcF | ((dstF & (BSIZE - 1u)) << 19), rec.y);
        slotbkt[pos] = (unsigned short)b;
    }
    __syncthreads();

    // pass 3: flush
    for (int i = t; i < cnt; i += BLK_SS) {
        int b = slotbkt[i];
        recB[(long long)(i + gdelta[b])] = stage[i];
    }
}

// ---------------- accumulate + combine ----------------

// deg from recA (src-partitioned 8B records): srcLocal = (x>>19)&1023.
__global__ __launch_bounds__(BLK_ACC)
void k_degaccA(const uint2* __restrict__ recs, const int* __restrict__ base,
               const int* __restrict__ hist, float* __restrict__ part, int split)
{
    __shared__ float lacc[BSIZE];
    const int b = blockIdx.x / split, sp = blockIdx.x % split;
    for (int i = threadIdx.x; i < BSIZE; i += blockDim.x) lacc[i] = 0.0f;
    __syncthreads();
    const int cnt = hist[b];
    const uint2* rp = recs + base[b];
    const int i0 = (int)((long long)cnt * sp / split);
    const int i1 = (int)((long long)cnt * (sp + 1) / split);
    for (int r = i0 + threadIdx.x; r < i1; r += blockDim.x) {
        uint2 rec = rp[r];
        atomicAdd(&lacc[(rec.x >> 19) & (BSIZE - 1u)], __uint_as_float(rec.y));
    }
    __syncthreads();
    float* dst = part + (size_t)(b * split + sp) * BSIZE;
    for (int i = threadIdx.x; i < BSIZE; i += blockDim.x)
        __builtin_nontemporal_store(lacc[i], dst + i);
}

// legacy deg from 4B records (one-pass fallback path)
__global__ __launch_bounds__(BLK_ACC)
void k_degacc4(const unsigned* __restrict__ recs, const int* __restrict__ base,
               const int* __restrict__ hist, float* __restrict__ part, int split)
{
    __shared__ float lacc[BSIZE];
    const int b = blockIdx.x / split, sp = blockIdx.x % split;
    for (int i = threadIdx.x; i < BSIZE; i += blockDim.x) lacc[i] = 0.0f;
    __syncthreads();
    const int cnt = hist[b];
    const unsigned* rp = recs + base[b];
    const int i0 = (int)((long long)cnt * sp / split);
    const int i1 = (int)((long long)cnt * (sp + 1) / split);
    for (int r = i0 + threadIdx.x; r < i1; r += blockDim.x) {
        unsigned rc = rp[r];
        atomicAdd(&lacc[rc & (BSIZE - 1u)], __uint_as_float(rc & 0xFFFFFC00u));
    }
    __syncthreads();
    float* dst = part + (size_t)(b * split + sp) * BSIZE;
    for (int i = threadIdx.x; i < BSIZE; i += blockDim.x)
        __builtin_nontemporal_store(lacc[i], dst + i);
}

// combine deg partials -> dinv, y0 = dinv*x
__global__ void k_degfin(const float* __restrict__ part, const float2* __restrict__ x,
                         float* __restrict__ dinv, float2* __restrict__ y0,
                         int n, int split)
{
    int node = blockIdx.x * blockDim.x + threadIdx.x;
    if (node >= n) return;
    int b = node >> BSHIFT, loc = node & (BSIZE - 1);
    float dg = 0.0f;
    for (int sp = 0; sp < split; ++sp)
        dg += part[(size_t)(b * split + sp) * BSIZE + loc];
    float di = (dg > 0.0f) ? rsqrtf(dg) : 0.0f;
    dinv[node] = di;
    float2 xv = x[node];
    y0[node] = make_float2(di * xv.x, di * xv.y);
}

// prop partial: plain loop; with recB's src-bucket grouping the y gathers
// fall in an ~8KB window per run (L1-local).
__global__ __launch_bounds__(BLK_ACC)
void k_propacc(const uint2* __restrict__ recs, const int* __restrict__ base,
               const int* __restrict__ hist, const float2* __restrict__ yin,
               float2* __restrict__ part, int split)
{
    __shared__ float lax[BSIZE];
    __shared__ float lay[BSIZE];
    const int b = blockIdx.x / split, sp = blockIdx.x % split;
    for (int i = threadIdx.x; i < BSIZE; i += blockDim.x) { lax[i] = 0.0f; lay[i] = 0.0f; }
    __syncthreads();
    const int cnt = hist[b];
    const uint2* rp = recs + base[b];
    const int i0 = (int)((long long)cnt * sp / split);
    const int i1 = (int)((long long)cnt * (sp + 1) / split);
    for (int r = i0 + threadIdx.x; r < i1; r += blockDim.x) {
        uint2 rec = rp[r];
        int s  = (int)(rec.x & 0x7FFFFu);
        int dl = (int)(rec.x >> 19);
        float wv = __uint_as_float(rec.y);
        float2 yv = yin[s];
        atomicAdd(&lax[dl], wv * yv.x);
        atomicAdd(&lay[dl], wv * yv.y);
    }
    __syncthreads();
    unsigned long long* dst =
        (unsigned long long*)(part + (size_t)(b * split + sp) * BSIZE);
    for (int i = threadIdx.x; i < BSIZE; i += blockDim.x) {
        unsigned long long pk = (unsigned long long)__float_as_uint(lax[i])
                              | ((unsigned long long)__float_as_uint(lay[i]) << 32);
        __builtin_nontemporal_store(pk, dst + i);
    }
}

// combine prop1 partials -> tx1 = -dinv*sum, y1 = dinv*tx1
__global__ void k_propfin1(const float2* __restrict__ part, const float* __restrict__ dinv,
                           float2* __restrict__ tx1, float2* __restrict__ y1,
                           int n, int split)
{
    int node = blockIdx.x * blockDim.x + threadIdx.x;
    if (node >= n) return;
    int b = node >> BSHIFT, loc = node & (BSIZE - 1);
    float sx = 0.0f, sy = 0.0f;
    for (int sp = 0; sp < split; ++sp) {
        float2 v = part[(size_t)(b * split + sp) * BSIZE + loc];
        sx += v.x; sy += v.y;
    }
    float di = dinv[node];
    float ox = -di * sx, oy = -di * sy;
    tx1[node] = make_float2(ox, oy);
    y1[node] = make_float2(di * ox, di * oy);
}

// combine prop2 partials + fused gates -> out
__global__ void k_propfin2(const float2* __restrict__ part, const float* __restrict__ dinv,
                           const float2* __restrict__ x, const float2* __restrict__ tx1,
                           const float* __restrict__ Wxz, const float* __restrict__ Wxh,
                           const float* __restrict__ bxz, const float* __restrict__ bhz,
                           const float* __restrict__ bxh, const float* __restrict__ bhh,
                           float* __restrict__ out, int n, int split)
{
    int node = blockIdx.x * blockDim.x + threadIdx.x;
    if (node >= n) return;
    int b = node >> BSHIFT, loc = node & (BSIZE - 1);
    float sx = 0.0f, sy = 0.0f;
    for (int sp = 0; sp < split; ++sp) {
        float2 v = part[(size_t)(b * split + sp) * BSIZE + loc];
        sx += v.x; sy += v.y;
    }
    float di = dinv[node];
    float2 t0 = x[node];
    float2 t1 = tx1[node];
    float t2x = 2.0f * (-di * sx) - t0.x;
    float t2y = 2.0f * (-di * sy) - t0.y;
    float z = t0.x * Wxz[0] + t0.y * Wxz[1]
            + t1.x * Wxz[2] + t1.y * Wxz[3]
            + t2x  * Wxz[4] + t2y  * Wxz[5] + bxz[0] + bhz[0];
    float h = t0.x * Wxh[0] + t0.y * Wxh[1]
            + t1.x * Wxh[2] + t1.y * Wxh[3]
            + t2x  * Wxh[4] + t2y  * Wxh[5] + bxh[0] + bhh[0];
    float zs = 1.0f / (1.0f + expf(-z));
    float ht = tanhf(h);
    out[node] = (1.0f - zs) * ht;
}

// ---------------- one-pass fallback sort (R7 structure) ----------------
template <int MODE>
__global__ __launch_bounds__(BLK_SS)
void k_sortscatter(const int* __restrict__ srcp, const int* __restrict__ dstp,
                   const float* __restrict__ w,
                   int* __restrict__ curS, int* __restrict__ curD,
                   unsigned* __restrict__ recS, uint2* __restrict__ recD,
                   long long ne, int NB, int NCH)
{
    __shared__ uint2 stage[SCH];
    __shared__ unsigned short slotbkt[SCH];
    __shared__ int loff[NBC_MAX];
    __shared__ int gdelta[NBC_MAX];
    __shared__ int stmp[BLK_SS];
    unsigned* stage0 = (unsigned*)stage;

    const int orig = blockIdx.x;
    const int xcd = orig & 7, idx = orig >> 3;
    const int q8 = NCH >> 3, r8 = NCH & 7;
    const int chunk = (xcd < r8 ? xcd * (q8 + 1) : r8 * (q8 + 1) + (xcd - r8) * q8) + idx;

    const long long cs = (long long)chunk * SCH;
    if (cs >= ne) return;
    const int cnt = (int)(((cs + SCH) < ne) ? SCH : (ne - cs));
    const int t = threadIdx.x;

    for (int phase = 0; phase < 2; ++phase) {
        if (!(MODE & (1 << phase))) continue;
        const int* keys = phase ? dstp : srcp;
        int* cur = phase ? curD : curS;

        for (int b = t; b < NB; b += BLK_SS) loff[b] = 0;
        __syncthreads();
        for (int i = t * 4; i < cnt; i += BLK_SS * 4) {
            if (i + 3 < cnt) {
                int4 k4 = *(const int4*)(keys + cs + i);
                atomicAdd(&loff[k4.x >> BSHIFT], 1); atomicAdd(&loff[k4.y >> BSHIFT], 1);
                atomicAdd(&loff[k4.z >> BSHIFT], 1); atomicAdd(&loff[k4.w >> BSHIFT], 1);
            } else {
                for (int q = i; q < cnt; ++q)
                    atomicAdd(&loff[keys[cs + q] >> BSHIFT], 1);
            }
        }
        __syncthreads();
        int v = (t < NB) ? loff[t] : 0;
        stmp[t] = v;
        __syncthreads();
        for (int off = 1; off < BLK_SS; off <<= 1) {
            int val = (t >= off) ? stmp[t - off] : 0;
            __syncthreads();
            stmp[t] += val;
            __syncthreads();
        }
        int excl = stmp[t] - v;
        if (t < NB) {
            int g = (v > 0) ? atomicAdd(&cur[t], v) : 0;
            loff[t] = excl;
            gdelta[t] = g - excl;
        }
        __syncthreads();
        for (int i = t * 4; i < cnt; i += BLK_SS * 4) {
            int lim = (i + 3 < cnt) ? 4 : (cnt - i > 0 ? cnt - i : 0);
            for (int j = 0; j < lim; ++j) {
                int q = i + j;
                int s = srcp[cs + q], d = dstp[cs + q];
                float we = (s == d) ? 0.0f : w[cs + q];
                int key = phase ? d : s;
                int b = key >> BSHIFT;
                int pos = atomicAdd(&loff[b], 1);
                if (phase) {
                    stage[pos] = make_uint2(
                        (unsigned)s | ((unsigned)(d & (BSIZE - 1)) << 19),
                        __float_as_uint(we));
                } else {
                    stage0[pos] = (__float_as_uint(we) & 0xFFFFFC00u)
                                | (unsigned)(s & (BSIZE - 1));
                }
                slotbkt[pos] = (unsigned short)b;
            }
        }
        __syncthreads();
        for (int i = t; i < cnt; i += BLK_SS) {
            int b = slotbkt[i];
            if (phase) recD[(long long)(i + gdelta[b])] = stage[i];
            else       recS[(long long)(i + gdelta[b])] = stage0[i];
        }
        __syncthreads();
    }
}

// ---------------- atomic fallback ----------------

__global__ void k_deg_atomic(const int* __restrict__ srcp, const int* __restrict__ dstp,
                             const float* __restrict__ w, float* __restrict__ deg,
                             long long ne)
{
    const long long ng = (ne + 3) >> 2;
    const long long stride = (long long)gridDim.x * blockDim.x;
    for (long long g = (long long)blockIdx.x * blockDim.x + threadIdx.x; g < ng; g += stride) {
        const long long e = g << 2;
        if (e + 3 < ne) {
            int4 s4 = *(const int4*)(srcp + e);
            int4 d4 = *(const int4*)(dstp + e);
            float4 w4 = *(const float4*)(w + e);
            if (s4.x != d4.x) atomAddF(&deg[s4.x], w4.x);
            if (s4.y != d4.y) atomAddF(&deg[s4.y], w4.y);
            if (s4.z != d4.z) atomAddF(&deg[s4.z], w4.z);
            if (s4.w != d4.w) atomAddF(&deg[s4.w], w4.w);
        } else {
            for (long long q = e; q < ne; ++q) {
                int s = srcp[q], d = dstp[q];
                if (s != d) atomAddF(&deg[s], w[q]);
            }
        }
    }
}

__global__ void k_dinv_inplace(float* __restrict__ deg, int n)
{
    int i = blockIdx.x * blockDim.x + threadIdx.x;
    if (i < n) {
        float d = deg[i];
        deg[i] = (d > 0.0f) ? rsqrtf(d) : 0.0f;
    }
}

__global__ void k_prop_atomic(const int* __restrict__ srcp, const int* __restrict__ dstp,
                              const float* __restrict__ w, const float* __restrict__ dinv,
                              const float2* __restrict__ xin, float* __restrict__ acc,
                              long long ne)
{
    const long long ng = (ne + 3) >> 2;
    const long long stride = (long long)gridDim.x * blockDim.x;
    for (long long g = (long long)blockIdx.x * blockDim.x + threadIdx.x; g < ng; g += stride) {
        const long long e = g << 2;
        if (e + 3 < ne) {
            int4 s4 = *(const int4*)(srcp + e);
            int4 d4 = *(const int4*)(dstp + e);
            float4 w4 = *(const float4*)(w + e);
            int s[4] = {s4.x, s4.y, s4.z, s4.w};
            int d[4] = {d4.x, d4.y, d4.z, d4.w};
            float wv[4] = {w4.x, w4.y, w4.z, w4.w};
#pragma unroll
            for (int j = 0; j < 4; ++j) {
                float wn = (s[j] != d[j]) ? -(dinv[s[j]] * wv[j] * dinv[d[j]]) : 0.0f;
                float2 xv = xin[s[j]];
                atomAddF(&acc[2 * d[j] + 0], wn * xv.x);
                atomAddF(&acc[2 * d[j] + 1], wn * xv.y);
            }
        } else {
            for (long long q = e; q < ne; ++q) {
                int ss = srcp[q], dd = dstp[q];
                float wn = (ss != dd) ? -(dinv[ss] * w[q] * dinv[dd]) : 0.0f;
                float2 xv = xin[ss];
                atomAddF(&acc[2 * dd + 0], wn * xv.x);
                atomAddF(&acc[2 * dd + 1], wn * xv.y);
            }
        }
    }
}

__global__ void k_final(const float2* __restrict__ x, const float2* __restrict__ tx1,
                        const float2* __restrict__ tx2a,
                        const float* __restrict__ Wxz, const float* __restrict__ Wxh,
                        const float* __restrict__ bxz, const float* __restrict__ bhz,
                        const float* __restrict__ bxh, const float* __restrict__ bhh,
                        float* __restrict__ out, int n)
{
    int i = blockIdx.x * blockDim.x + threadIdx.x;
    if (i >= n) return;
    float2 t0 = x[i];
    float2 t1 = tx1[i];
    float2 ta = tx2a[i];
    float t2x = 2.0f * ta.x - t0.x;
    float t2y = 2.0f * ta.y - t0.y;
    float z = t0.x * Wxz[0] + t0.y * Wxz[1]
            + t1.x * Wxz[2] + t1.y * Wxz[3]
            + t2x  * Wxz[4] + t2y  * Wxz[5] + bxz[0] + bhz[0];
    float h = t0.x * Wxh[0] + t0.y * Wxh[1]
            + t1.x * Wxh[2] + t1.y * Wxh[3]
            + t2x  * Wxh[4] + t2y  * Wxh[5] + bxh[0] + bhh[0];
    float zs = 1.0f / (1.0f + expf(-z));
    float ht = tanhf(h);
    out[i] = (1.0f - zs) * ht;
}

// ---------------- launch ----------------

extern "C" void kernel_launch(void* const* d_in, const int* in_sizes, int n_in,
                              void* d_out, int out_size, void* d_ws, size_t ws_size,
                              hipStream_t stream)
{
    const float* x   = (const float*)d_in[0];
    const int*   ei  = (const int*)d_in[1];
    const float* w   = (const float*)d_in[2];
    const float* Wxz = (const float*)d_in[3];
    const float* Wxh = (const float*)d_in[5];
    const float* bxz = (const float*)d_in[9];
    const float* bhz = (const float*)d_in[10];
    const float* bxh = (const float*)d_in[13];
    const float* bhh = (const float*)d_in[14];

    const int n = in_sizes[0] / 2;
    const long long ne = in_sizes[2];
    const int* srcp = ei;
    const int* dstp = ei + ne;
    const int nblocks = (n + BLK - 1) / BLK;
    const int NBC = (n + BSIZE - 1) >> BSHIFT;
    const int NCH = (int)((ne + SCH - 1) / SCH);
    char* ws = (char*)d_ws;

    const bool nodes_ok = (n <= (1 << 19)) && (NBC <= NBC_MAX);
    const int split = 8;

    auto align256 = [](size_t v) { return (v + 255) & ~(size_t)255; };
    const size_t recBytes  = align256((size_t)ne * 8);
    const size_t dinvBytes = align256((size_t)n * 4);
    const size_t vecBytes  = align256((size_t)n * 8);
    const size_t histBytes = align256((size_t)NBC_MAX * 4);
    const size_t partPropBytes = (size_t)NBC * split * BSIZE * 8;
    const size_t partDegBytes  = (size_t)NBC * split * BSIZE * 4;

    // two-pass layout: recA, recB, dinv, y0, y1, tx1, 6x hist
    size_t off = 0;
    char* pRecA = ws + off; off += recBytes;
    char* pRecB = ws + off; off += recBytes;
    char* pDinv = ws + off; off += dinvBytes;
    char* pY0   = ws + off; off += vecBytes;
    char* pY1   = ws + off; off += vecBytes;
    char* pTx1  = ws + off; off += vecBytes;
    char* pHist = ws + off; off += 6 * histBytes;
    const size_t need_twopass = off;
    const bool twopass = nodes_ok && (need_twopass <= ws_size)
                       && (partPropBytes <= recBytes) && (partDegBytes <= recBytes);

    if (twopass) {
        uint2* recA = (uint2*)pRecA;
        uint2* recB = (uint2*)pRecB;
        float* dinv = (float*)pDinv;
        float2* y0  = (float2*)pY0;
        float2* y1  = (float2*)pY1;
        float2* tx1 = (float2*)pTx1;
        int* histS = (int*)pHist;
        int* histD = (int*)(pHist + histBytes);
        int* baseS = (int*)(pHist + 2 * histBytes);
        int* baseD = (int*)(pHist + 3 * histBytes);
        int* curS  = (int*)(pHist + 4 * histBytes);
        int* curD  = (int*)(pHist + 5 * histBytes);
        float* partDeg  = (float*)pRecB;   // dead until k_sortB writes recB
        float* partProp = (float*)pRecA;   // recA dead after k_sortB

        k_zero_ints<<<(2 * NBC_MAX + BLK - 1) / BLK, BLK, 0, stream>>>(histS, 2 * NBC_MAX);
        k_hist<<<2048, BLK, 0, stream>>>(srcp, dstp, histS, histD, ne, NBC);
        k_scan<<<2, BLK, 0, stream>>>(histS, baseS, curS, histD, baseD, curD, NBC);
        k_sortA<<<NCH, BLK_SS, 0, stream>>>(srcp, dstp, w, curS, recA, ne, NBC, NCH);
        k_degaccA<<<NBC * split, BLK_ACC, 0, stream>>>(recA, baseS, histS, partDeg, split);
        k_degfin<<<nblocks, BLK, 0, stream>>>(partDeg, (const float2*)x, dinv, y0, n, split);
        k_sortB<<<NCH, BLK_SS, 0, stream>>>(recA, baseS, curD, recB, ne, NBC, NCH);
        k_propacc<<<NBC * split, BLK_ACC, 0, stream>>>(recB, baseD, histD, y0,
                                                       (float2*)partProp, split);
        k_propfin1<<<nblocks, BLK, 0, stream>>>((const float2*)partProp, dinv,
                                                tx1, y1, n, split);
        k_propacc<<<NBC * split, BLK_ACC, 0, stream>>>(recB, baseD, histD, y1,
                                                       (float2*)partProp, split);
        k_propfin2<<<nblocks, BLK, 0, stream>>>((const float2*)partProp, dinv,
                                                (const float2*)x, tx1,
                                                Wxz, Wxh, bxz, bhz, bxh, bhh,
                                                (float*)d_out, n, split);
        return;
    }

    // one-pass layout (R7 structure): recD(8B), recS(4B), vectors, part, hists
    off = 0;
    char* pRecD = ws + off; off += recBytes;
    char* pRecS = ws + off; off += align256((size_t)ne * 4);
    char* qDinv = ws + off; off += dinvBytes;
    char* qY0   = ws + off; off += vecBytes;
    char* qY1   = ws + off; off += vecBytes;
    char* qTx1  = ws + off; off += vecBytes;
    char* qPart = ws + off; off += align256(partPropBytes);
    char* qHist = ws + off; off += 6 * histBytes;
    const bool onepass = nodes_ok && (off <= ws_size);

    if (onepass) {
        uint2* recD = (uint2*)pRecD;
        unsigned* recS = (unsigned*)pRecS;
        float* dinv = (float*)qDinv;
        float2* y0  = (float2*)qY0;
        float2* y1  = (float2*)qY1;
        float2* tx1 = (float2*)qTx1;
        float* part = (float*)qPart;
        int* histS = (int*)qHist;
        int* histD = (int*)(qHist + histBytes);
        int* baseS = (int*)(qHist + 2 * histBytes);
        int* baseD = (int*)(qHist + 3 * histBytes);
        int* curS  = (int*)(qHist + 4 * histBytes);
        int* curD  = (int*)(qHist + 5 * histBytes);

        k_zero_ints<<<(2 * NBC_MAX + BLK - 1) / BLK, BLK, 0, stream>>>(histS, 2 * NBC_MAX);
        k_hist<<<2048, BLK, 0, stream>>>(srcp, dstp, histS, histD, ne, NBC);
        k_scan<<<2, BLK, 0, stream>>>(histS, baseS, curS, histD, baseD, curD, NBC);
        k_sortscatter<3><<<NCH, BLK_SS, 0, stream>>>(srcp, dstp, w, curS, curD,
                                                     recS, recD, ne, NBC, NCH);
        k_degacc4<<<NBC * split, BLK_ACC, 0, stream>>>(recS, baseS, histS, part, split);
        k_degfin<<<nblocks, BLK, 0, stream>>>(part, (const float2*)x, dinv, y0, n, split);
        k_propacc<<<NBC * split, BLK_ACC, 0, stream>>>(recD, baseD, histD, y0,
                                                       (float2*)part, split);
        k_propfin1<<<nblocks, BLK, 0, stream>>>((const float2*)part, dinv, tx1, y1, n, split);
        k_propacc<<<NBC * split, BLK_ACC, 0, stream>>>(recD, baseD, histD, y1,
                                                       (float2*)part, split);
        k_propfin2<<<nblocks, BLK, 0, stream>>>((const float2*)part, dinv,
                                                (const float2*)x, tx1,
                                                Wxz, Wxh, bxz, bhz, bxh, bhh,
                                                (float*)d_out, n, split);
        return;
    }

    // last-resort: global-atomic path
    size_t foff = 0;
    auto falloc = [&](size_t bytes) -> char* {
        char* p = ws + foff;
        foff = (foff + bytes + 255) & ~(size_t)255;
        return p;
    };
    float* deg   = (float*)falloc((size_t)n * sizeof(float));
    float* ftx1  = (float*)falloc((size_t)n * 2 * sizeof(float));
    float* ftx2a = (float*)falloc((size_t)n * 2 * sizeof(float));
    const long long n4 = (long long)(foff / 16);
    k_zero_f4<<<1024, BLK, 0, stream>>>((float4*)ws, n4);
    k_deg_atomic<<<4096, BLK, 0, stream>>>(srcp, dstp, w, deg, ne);
    k_dinv_inplace<<<nblocks, BLK, 0, stream>>>(deg, n);
    k_prop_atomic<<<4096, BLK, 0, stream>>>(srcp, dstp, w, deg,
                                            (const float2*)x, ftx1, ne);
    k_prop_atomic<<<4096, BLK, 0, stream>>>(srcp, dstp, w, deg,
                                            (const float2*)ftx1, ftx2a, ne);
    k_final<<<nblocks, BLK, 0, stream>>>((const float2*)x, (const float2*)ftx1,
                                         (const float2*)ftx2a,
                                         Wxz, Wxh, bxz, bhz, bxh, bhh,
                                         (float*)d_out, n);
}

// Round 14
// 640.280 us; speedup vs baseline: 1.1600x; 1.1600x over previous
//
#include <hip/hip_runtime.h>

// GConvGRU (ChebConv K=3, GRU with H=0) on MI355X.
// H=0 => out = (1 - sigmoid(Cz + bhz)) * tanh(Ch + bhh); Cz/Ch share the
// Chebyshev basis Tx0=x, Tx1=P x, Tx2=2 P Tx1 - x, P = -D^{-1/2} A D^{-1/2}.
// Factorization: P v = -dinv .* (A_w^T (dinv .* v)), so records store raw w.
//
// R13: locality fix cut FETCH 190->66MB but propacc stuck at 176us (6th
// null intervention). Remaining suspects: TA divergence vs LDS float-atomic
// CAS lowering. THIS ROUND = within-round A/B: prop pass1 keeps float LDS
// atomics (control); pass2 uses fixed-point ds_add_u32 (treatment, native).

static constexpr int BLK = 256;
static constexpr int BLK_SS = 512;      // sort block
static constexpr int BLK_ACC = 512;
static constexpr int NBC_MAX = 512;     // max coarse buckets (n <= 2^19)
static constexpr int BSHIFT = 10;       // 1024 nodes/bucket
static constexpr int BSIZE = 1024;
static constexpr int SCH = 4096;        // records per sort chunk

__device__ __forceinline__ void atomAddF(float* p, float v) {
    unsafeAtomicAdd(p, v);
}

// ---------------- utility ----------------

__global__ void k_zero_ints(int* __restrict__ p, int n)
{
    int i = blockIdx.x * blockDim.x + threadIdx.x;
    if (i < n) p[i] = 0;
}

__global__ void k_zero_f4(float4* __restrict__ p, long long n4)
{
    long long i = (long long)blockIdx.x * blockDim.x + threadIdx.x;
    long long stride = (long long)gridDim.x * blockDim.x;
    for (; i < n4; i += stride) p[i] = make_float4(0.f, 0.f, 0.f, 0.f);
}

// ---------------- histogram + scan ----------------

__global__ void k_hist(const int* __restrict__ srcp, const int* __restrict__ dstp,
                       int* __restrict__ histS, int* __restrict__ histD,
                       long long ne, int NB)
{
    __shared__ int lS[NBC_MAX];
    __shared__ int lD[NBC_MAX];
    for (int b = threadIdx.x; b < NB; b += blockDim.x) { lS[b] = 0; lD[b] = 0; }
    __syncthreads();

    const long long ng = (ne + 3) >> 2;
    const long long stride = (long long)gridDim.x * blockDim.x;
    for (long long g = (long long)blockIdx.x * blockDim.x + threadIdx.x; g < ng; g += stride) {
        const long long e = g << 2;
        if (e + 3 < ne) {
            int4 s4 = *(const int4*)(srcp + e);
            int4 d4 = *(const int4*)(dstp + e);
            atomicAdd(&lS[s4.x >> BSHIFT], 1); atomicAdd(&lS[s4.y >> BSHIFT], 1);
            atomicAdd(&lS[s4.z >> BSHIFT], 1); atomicAdd(&lS[s4.w >> BSHIFT], 1);
            atomicAdd(&lD[d4.x >> BSHIFT], 1); atomicAdd(&lD[d4.y >> BSHIFT], 1);
            atomicAdd(&lD[d4.z >> BSHIFT], 1); atomicAdd(&lD[d4.w >> BSHIFT], 1);
        } else {
            for (long long q = e; q < ne; ++q) {
                atomicAdd(&lS[srcp[q] >> BSHIFT], 1);
                atomicAdd(&lD[dstp[q] >> BSHIFT], 1);
            }
        }
    }
    __syncthreads();
    for (int b = threadIdx.x; b < NB; b += blockDim.x) {
        if (lS[b]) atomicAdd(&histS[b], lS[b]);
        if (lD[b]) atomicAdd(&histD[b], lD[b]);
    }
}

// Exclusive scan: block 0 does S, block 1 does D. NB <= 512, BLK=256.
__global__ void k_scan(const int* __restrict__ histS, int* __restrict__ baseS, int* __restrict__ curS,
                       const int* __restrict__ histD, int* __restrict__ baseD, int* __restrict__ curD,
                       int NB)
{
    const int* hist = (blockIdx.x == 0) ? histS : histD;
    int* base = (blockIdx.x == 0) ? baseS : baseD;
    int* cur  = (blockIdx.x == 0) ? curS  : curD;

    __shared__ int part[BLK];
    int t = threadIdx.x;
    int v0 = (2 * t     < NB) ? hist[2 * t]     : 0;
    int v1 = (2 * t + 1 < NB) ? hist[2 * t + 1] : 0;
    part[t] = v0 + v1;
    __syncthreads();
    for (int off = 1; off < BLK; off <<= 1) {
        int val = (t >= off) ? part[t - off] : 0;
        __syncthreads();
        part[t] += val;
        __syncthreads();
    }
    int run = (t == 0) ? 0 : part[t - 1];
    if (2 * t < NB)     { base[2 * t] = run;          cur[2 * t] = run; }
    if (2 * t + 1 < NB) { base[2 * t + 1] = run + v0; cur[2 * t + 1] = run + v0; }
}

// ---------------- pass A: sort raw edges by src-bucket ----------------
// recA = { dst(19b) | srcLocal(10b)<<19 , w_full } (w=0 for self-loops)
__global__ __launch_bounds__(BLK_SS)
void k_sortA(const int* __restrict__ srcp, const int* __restrict__ dstp,
             const float* __restrict__ w, int* __restrict__ curS,
             uint2* __restrict__ recA, long long ne, int NB, int NCH)
{
    __shared__ uint2 stage[SCH];            // 32 KB
    __shared__ unsigned short slotbkt[SCH]; // 8 KB
    __shared__ int loff[NBC_MAX];
    __shared__ int gdelta[NBC_MAX];
    __shared__ int stmp[BLK_SS];

    const int orig = blockIdx.x;
    const int xcd = orig & 7, idx = orig >> 3;
    const int q8 = NCH >> 3, r8 = NCH & 7;
    const int chunk = (xcd < r8 ? xcd * (q8 + 1) : r8 * (q8 + 1) + (xcd - r8) * q8) + idx;

    const long long cs = (long long)chunk * SCH;
    if (cs >= ne) return;
    const int cnt = (int)(((cs + SCH) < ne) ? SCH : (ne - cs));
    const int t = threadIdx.x;

    for (int b = t; b < NB; b += BLK_SS) loff[b] = 0;
    __syncthreads();

    for (int i = t * 4; i < cnt; i += BLK_SS * 4) {
        if (i + 3 < cnt) {
            int4 k4 = *(const int4*)(srcp + cs + i);
            atomicAdd(&loff[k4.x >> BSHIFT], 1); atomicAdd(&loff[k4.y >> BSHIFT], 1);
            atomicAdd(&loff[k4.z >> BSHIFT], 1); atomicAdd(&loff[k4.w >> BSHIFT], 1);
        } else {
            for (int q = i; q < cnt; ++q)
                atomicAdd(&loff[srcp[cs + q] >> BSHIFT], 1);
        }
    }
    __syncthreads();

    int v = (t < NB) ? loff[t] : 0;
    stmp[t] = v;
    __syncthreads();
    for (int off = 1; off < BLK_SS; off <<= 1) {
        int val = (t >= off) ? stmp[t - off] : 0;
        __syncthreads();
        stmp[t] += val;
        __syncthreads();
    }
    int excl = stmp[t] - v;
    if (t < NB) {
        int g = (v > 0) ? atomicAdd(&curS[t], v) : 0;
        loff[t] = excl;
        gdelta[t] = g - excl;
    }
    __syncthreads();

    for (int i = t * 4; i < cnt; i += BLK_SS * 4) {
        if (i + 3 < cnt) {
            int4 s4 = *(const int4*)(srcp + cs + i);
            int4 d4 = *(const int4*)(dstp + cs + i);
            float4 w4 = *(const float4*)(w + cs + i);
            int ss[4] = {s4.x, s4.y, s4.z, s4.w};
            int dd[4] = {d4.x, d4.y, d4.z, d4.w};
            float wv[4] = {w4.x, w4.y, w4.z, w4.w};
#pragma unroll
            for (int j = 0; j < 4; ++j) {
                float we = (ss[j] == dd[j]) ? 0.0f : wv[j];
                int b = ss[j] >> BSHIFT;
                int pos = atomicAdd(&loff[b], 1);
                stage[pos] = make_uint2(
                    (unsigned)dd[j] | ((unsigned)(ss[j] & (BSIZE - 1)) << 19),
                    __float_as_uint(we));
                slotbkt[pos] = (unsigned short)b;
            }
        } else {
            for (int q = i; q < cnt; ++q) {
                int s = srcp[cs + q], d = dstp[cs + q];
                float we = (s == d) ? 0.0f : w[cs + q];
                int b = s >> BSHIFT;
                int pos = atomicAdd(&loff[b], 1);
                stage[pos] = make_uint2(
                    (unsigned)d | ((unsigned)(s & (BSIZE - 1)) << 19),
                    __float_as_uint(we));
                slotbkt[pos] = (unsigned short)b;
            }
        }
    }
    __syncthreads();

    for (int i = t; i < cnt; i += BLK_SS) {
        int b = slotbkt[i];
        recA[(long long)(i + gdelta[b])] = stage[i];
    }
}

// ---------------- pass B: re-sort recA by dst-bucket ----------------
__global__ __launch_bounds__(BLK_SS)
void k_sortB(const uint2* __restrict__ recA, const int* __restrict__ baseS,
             int* __restrict__ curD, uint2* __restrict__ recB,
             long long ne, int NB, int NCH)
{
    __shared__ uint2 stage[SCH];
    __shared__ unsigned short slotbkt[SCH];
    __shared__ int loff[NBC_MAX];
    __shared__ int gdelta[NBC_MAX];
    __shared__ int stmp[BLK_SS];
    __shared__ int lbaseS[NBC_MAX];

    const int orig = blockIdx.x;
    const int xcd = orig & 7, idx = orig >> 3;
    const int q8 = NCH >> 3, r8 = NCH & 7;
    const int chunk = (xcd < r8 ? xcd * (q8 + 1) : r8 * (q8 + 1) + (xcd - r8) * q8) + idx;

    const long long cs = (long long)chunk * SCH;
    if (cs >= ne) return;
    const int cnt = (int)(((cs + SCH) < ne) ? SCH : (ne - cs));
    const int t = threadIdx.x;

    for (int b = t; b < NB; b += BLK_SS) { loff[b] = 0; lbaseS[b] = baseS[b]; }
    __syncthreads();

    for (int i = t * 2; i < cnt; i += BLK_SS * 2) {
        if (i + 1 < cnt) {
            uint4 two = *(const uint4*)(recA + cs + i);
            atomicAdd(&loff[(two.x & 0x7FFFFu) >> BSHIFT], 1);
            atomicAdd(&loff[(two.z & 0x7FFFFu) >> BSHIFT], 1);
        } else {
            uint2 one = recA[cs + i];
            atomicAdd(&loff[(one.x & 0x7FFFFu) >> BSHIFT], 1);
        }
    }
    __syncthreads();

    int v = (t < NB) ? loff[t] : 0;
    stmp[t] = v;
    __syncthreads();
    for (int off = 1; off < BLK_SS; off <<= 1) {
        int val = (t >= off) ? stmp[t - off] : 0;
        __syncthreads();
        stmp[t] += val;
        __syncthreads();
    }
    int excl = stmp[t] - v;
    if (t < NB) {
        int g = (v > 0) ? atomicAdd(&curD[t], v) : 0;
        loff[t] = excl;
        gdelta[t] = g - excl;
    }
    __syncthreads();

    for (int i = t; i < cnt; i += BLK_SS) {
        uint2 rec = recA[cs + i];
        int p;
        {
            long long gp = cs + i;
            int lo = 0, hi = NB;
            while (hi - lo > 1) {
                int mid = (lo + hi) >> 1;
                if ((long long)lbaseS[mid] <= gp) lo = mid; else hi = mid;
            }
            p = lo;
        }
        unsigned dstF = rec.x & 0x7FFFFu;
        unsigned srcL = (rec.x >> 19) & (BSIZE - 1u);
        unsigned srcF = ((unsigned)p << BSHIFT) | srcL;
        int b = (int)(dstF >> BSHIFT);
        int pos = atomicAdd(&loff[b], 1);
        stage[pos] = make_uint2(srcF | ((dstF & (BSIZE - 1u)) << 19), rec.y);
        slotbkt[pos] = (unsigned short)b;
    }
    __syncthreads();

    for (int i = t; i < cnt; i += BLK_SS) {
        int b = slotbkt[i];
        recB[(long long)(i + gdelta[b])] = stage[i];
    }
}

// ---------------- accumulate + combine ----------------

__global__ __launch_bounds__(BLK_ACC)
void k_degaccA(const uint2* __restrict__ recs, const int* __restrict__ base,
               const int* __restrict__ hist, float* __restrict__ part, int split)
{
    __shared__ float lacc[BSIZE];
    const int b = blockIdx.x / split, sp = blockIdx.x % split;
    for (int i = threadIdx.x; i < BSIZE; i += blockDim.x) lacc[i] = 0.0f;
    __syncthreads();
    const int cnt = hist[b];
    const uint2* rp = recs + base[b];
    const int i0 = (int)((long long)cnt * sp / split);
    const int i1 = (int)((long long)cnt * (sp + 1) / split);
    for (int r = i0 + threadIdx.x; r < i1; r += blockDim.x) {
        uint2 rec = rp[r];
        atomicAdd(&lacc[(rec.x >> 19) & (BSIZE - 1u)], __uint_as_float(rec.y));
    }
    __syncthreads();
    float* dst = part + (size_t)(b * split + sp) * BSIZE;
    for (int i = threadIdx.x; i < BSIZE; i += blockDim.x)
        __builtin_nontemporal_store(lacc[i], dst + i);
}

__global__ void k_degfin(const float* __restrict__ part, const float2* __restrict__ x,
                         float* __restrict__ dinv, float2* __restrict__ y0,
                         int n, int split)
{
    int node = blockIdx.x * blockDim.x + threadIdx.x;
    if (node >= n) return;
    int b = node >> BSHIFT, loc = node & (BSIZE - 1);
    float dg = 0.0f;
    for (int sp = 0; sp < split; ++sp)
        dg += part[(size_t)(b * split + sp) * BSIZE + loc];
    float di = (dg > 0.0f) ? rsqrtf(dg) : 0.0f;
    dinv[node] = di;
    float2 xv = x[node];
    y0[node] = make_float2(di * xv.x, di * xv.y);
}

// prop partial. VAR 0: float LDS atomics (control).
// VAR 1: fixed-point ds_add_u32 (treatment) — scale 2^20, exact signed wrap.
template <int VAR>
__global__ __launch_bounds__(BLK_ACC)
void k_propacc(const uint2* __restrict__ recs, const int* __restrict__ base,
               const int* __restrict__ hist, const float2* __restrict__ yin,
               float2* __restrict__ part, int split)
{
    __shared__ float lax[BSIZE];
    __shared__ float lay[BSIZE];
    int* iax = (int*)lax;
    int* iay = (int*)lay;
    const float S = 1048576.0f;          // 2^20
    const float INVS = 1.0f / 1048576.0f;

    const int b = blockIdx.x / split, sp = blockIdx.x % split;
    for (int i = threadIdx.x; i < BSIZE; i += blockDim.x) {
        if (VAR == 0) { lax[i] = 0.0f; lay[i] = 0.0f; }
        else          { iax[i] = 0;    iay[i] = 0;    }
    }
    __syncthreads();
    const int cnt = hist[b];
    const uint2* rp = recs + base[b];
    const int i0 = (int)((long long)cnt * sp / split);
    const int i1 = (int)((long long)cnt * (sp + 1) / split);
    for (int r = i0 + threadIdx.x; r < i1; r += blockDim.x) {
        uint2 rec = rp[r];
        int s  = (int)(rec.x & 0x7FFFFu);
        int dl = (int)(rec.x >> 19);
        float wv = __uint_as_float(rec.y);
        float2 yv = yin[s];
        if (VAR == 0) {
            atomicAdd(&lax[dl], wv * yv.x);
            atomicAdd(&lay[dl], wv * yv.y);
        } else {
            atomicAdd(&iax[dl], __float2int_rn(wv * yv.x * S));
            atomicAdd(&iay[dl], __float2int_rn(wv * yv.y * S));
        }
    }
    __syncthreads();
    unsigned long long* dst =
        (unsigned long long*)(part + (size_t)(b * split + sp) * BSIZE);
    for (int i = threadIdx.x; i < BSIZE; i += blockDim.x) {
        float fx = (VAR == 0) ? lax[i] : (float)iax[i] * INVS;
        float fy = (VAR == 0) ? lay[i] : (float)iay[i] * INVS;
        unsigned long long pk = (unsigned long long)__float_as_uint(fx)
                              | ((unsigned long long)__float_as_uint(fy) << 32);
        __builtin_nontemporal_store(pk, dst + i);
    }
}

__global__ void k_propfin1(const float2* __restrict__ part, const float* __restrict__ dinv,
                           float2* __restrict__ tx1, float2* __restrict__ y1,
                           int n, int split)
{
    int node = blockIdx.x * blockDim.x + threadIdx.x;
    if (node >= n) return;
    int b = node >> BSHIFT, loc = node & (BSIZE - 1);
    float sx = 0.0f, sy = 0.0f;
    for (int sp = 0; sp < split; ++sp) {
        float2 v = part[(size_t)(b * split + sp) * BSIZE + loc];
        sx += v.x; sy += v.y;
    }
    float di = dinv[node];
    float ox = -di * sx, oy = -di * sy;
    tx1[node] = make_float2(ox, oy);
    y1[node] = make_float2(di * ox, di * oy);
}

__global__ void k_propfin2(const float2* __restrict__ part, const float* __restrict__ dinv,
                           const float2* __restrict__ x, const float2* __restrict__ tx1,
                           const float* __restrict__ Wxz, const float* __restrict__ Wxh,
                           const float* __restrict__ bxz, const float* __restrict__ bhz,
                           const float* __restrict__ bxh, const float* __restrict__ bhh,
                           float* __restrict__ out, int n, int split)
{
    int node = blockIdx.x * blockDim.x + threadIdx.x;
    if (node >= n) return;
    int b = node >> BSHIFT, loc = node & (BSIZE - 1);
    float sx = 0.0f, sy = 0.0f;
    for (int sp = 0; sp < split; ++sp) {
        float2 v = part[(size_t)(b * split + sp) * BSIZE + loc];
        sx += v.x; sy += v.y;
    }
    float di = dinv[node];
    float2 t0 = x[node];
    float2 t1 = tx1[node];
    float t2x = 2.0f * (-di * sx) - t0.x;
    float t2y = 2.0f * (-di * sy) - t0.y;
    float z = t0.x * Wxz[0] + t0.y * Wxz[1]
            + t1.x * Wxz[2] + t1.y * Wxz[3]
            + t2x  * Wxz[4] + t2y  * Wxz[5] + bxz[0] + bhz[0];
    float h = t0.x * Wxh[0] + t0.y * Wxh[1]
            + t1.x * Wxh[2] + t1.y * Wxh[3]
            + t2x  * Wxh[4] + t2y  * Wxh[5] + bxh[0] + bhh[0];
    float zs = 1.0f / (1.0f + expf(-z));
    float ht = tanhf(h);
    out[node] = (1.0f - zs) * ht;
}

// ---------------- atomic fallback ----------------

__global__ void k_deg_atomic(const int* __restrict__ srcp, const int* __restrict__ dstp,
                             const float* __restrict__ w, float* __restrict__ deg,
                             long long ne)
{
    const long long ng = (ne + 3) >> 2;
    const long long stride = (long long)gridDim.x * blockDim.x;
    for (long long g = (long long)blockIdx.x * blockDim.x + threadIdx.x; g < ng; g += stride) {
        const long long e = g << 2;
        if (e + 3 < ne) {
            int4 s4 = *(const int4*)(srcp + e);
            int4 d4 = *(const int4*)(dstp + e);
            float4 w4 = *(const float4*)(w + e);
            if (s4.x != d4.x) atomAddF(&deg[s4.x], w4.x);
            if (s4.y != d4.y) atomAddF(&deg[s4.y], w4.y);
            if (s4.z != d4.z) atomAddF(&deg[s4.z], w4.z);
            if (s4.w != d4.w) atomAddF(&deg[s4.w], w4.w);
        } else {
            for (long long q = e; q < ne; ++q) {
                int s = srcp[q], d = dstp[q];
                if (s != d) atomAddF(&deg[s], w[q]);
            }
        }
    }
}

__global__ void k_dinv_inplace(float* __restrict__ deg, int n)
{
    int i = blockIdx.x * blockDim.x + threadIdx.x;
    if (i < n) {
        float d = deg[i];
        deg[i] = (d > 0.0f) ? rsqrtf(d) : 0.0f;
    }
}

__global__ void k_prop_atomic(const int* __restrict__ srcp, const int* __restrict__ dstp,
                              const float* __restrict__ w, const float* __restrict__ dinv,
                              const float2* __restrict__ xin, float* __restrict__ acc,
                              long long ne)
{
    const long long ng = (ne + 3) >> 2;
    const long long stride = (long long)gridDim.x * blockDim.x;
    for (long long g = (long long)blockIdx.x * blockDim.x + threadIdx.x; g < ng; g += stride) {
        const long long e = g << 2;
        if (e + 3 < ne) {
            int4 s4 = *(const int4*)(srcp + e);
            int4 d4 = *(const int4*)(dstp + e);
            float4 w4 = *(const float4*)(w + e);
            int s[4] = {s4.x, s4.y, s4.z, s4.w};
            int d[4] = {d4.x, d4.y, d4.z, d4.w};
            float wv[4] = {w4.x, w4.y, w4.z, w4.w};
#pragma unroll
            for (int j = 0; j < 4; ++j) {
                float wn = (s[j] != d[j]) ? -(dinv[s[j]] * wv[j] * dinv[d[j]]) : 0.0f;
                float2 xv = xin[s[j]];
                atomAddF(&acc[2 * d[j] + 0], wn * xv.x);
                atomAddF(&acc[2 * d[j] + 1], wn * xv.y);
            }
        } else {
            for (long long q = e; q < ne; ++q) {
                int ss = srcp[q], dd = dstp[q];
                float wn = (ss != dd) ? -(dinv[ss] * w[q] * dinv[dd]) : 0.0f;
                float2 xv = xin[ss];
                atomAddF(&acc[2 * dd + 0], wn * xv.x);
                atomAddF(&acc[2 * dd + 1], wn * xv.y);
            }
        }
    }
}

__global__ void k_final(const float2* __restrict__ x, const float2* __restrict__ tx1,
                        const float2* __restrict__ tx2a,
                        const float* __restrict__ Wxz, const float* __restrict__ Wxh,
                        const float* __restrict__ bxz, const float* __restrict__ bhz,
                        const float* __restrict__ bxh, const float* __restrict__ bhh,
                        float* __restrict__ out, int n)
{
    int i = blockIdx.x * blockDim.x + threadIdx.x;
    if (i >= n) return;
    float2 t0 = x[i];
    float2 t1 = tx1[i];
    float2 ta = tx2a[i];
    float t2x = 2.0f * ta.x - t0.x;
    float t2y = 2.0f * ta.y - t0.y;
    float z = t0.x * Wxz[0] + t0.y * Wxz[1]
            + t1.x * Wxz[2] + t1.y * Wxz[3]
            + t2x  * Wxz[4] + t2y  * Wxz[5] + bxz[0] + bhz[0];
    float h = t0.x * Wxh[0] + t0.y * Wxh[1]
            + t1.x * Wxh[2] + t1.y * Wxh[3]
            + t2x  * Wxh[4] + t2y  * Wxh[5] + bxh[0] + bhh[0];
    float zs = 1.0f / (1.0f + expf(-z));
    float ht = tanhf(h);
    out[i] = (1.0f - zs) * ht;
}

// ---------------- launch ----------------

extern "C" void kernel_launch(void* const* d_in, const int* in_sizes, int n_in,
                              void* d_out, int out_size, void* d_ws, size_t ws_size,
                              hipStream_t stream)
{
    const float* x   = (const float*)d_in[0];
    const int*   ei  = (const int*)d_in[1];
    const float* w   = (const float*)d_in[2];
    const float* Wxz = (const float*)d_in[3];
    const float* Wxh = (const float*)d_in[5];
    const float* bxz = (const float*)d_in[9];
    const float* bhz = (const float*)d_in[10];
    const float* bxh = (const float*)d_in[13];
    const float* bhh = (const float*)d_in[14];

    const int n = in_sizes[0] / 2;
    const long long ne = in_sizes[2];
    const int* srcp = ei;
    const int* dstp = ei + ne;
    const int nblocks = (n + BLK - 1) / BLK;
    const int NBC = (n + BSIZE - 1) >> BSHIFT;
    const int NCH = (int)((ne + SCH - 1) / SCH);
    char* ws = (char*)d_ws;

    const bool nodes_ok = (n <= (1 << 19)) && (NBC <= NBC_MAX);
    const int split = 8;

    auto align256 = [](size_t v) { return (v + 255) & ~(size_t)255; };
    const size_t recBytes  = align256((size_t)ne * 8);
    const size_t dinvBytes = align256((size_t)n * 4);
    const size_t vecBytes  = align256((size_t)n * 8);
    const size_t histBytes = align256((size_t)NBC_MAX * 4);
    const size_t partPropBytes = (size_t)NBC * split * BSIZE * 8;
    const size_t partDegBytes  = (size_t)NBC * split * BSIZE * 4;

    size_t off = 0;
    char* pRecA = ws + off; off += recBytes;
    char* pRecB = ws + off; off += recBytes;
    char* pDinv = ws + off; off += dinvBytes;
    char* pY0   = ws + off; off += vecBytes;
    char* pY1   = ws + off; off += vecBytes;
    char* pTx1  = ws + off; off += vecBytes;
    char* pHist = ws + off; off += 6 * histBytes;
    const size_t need_twopass = off;
    const bool twopass = nodes_ok && (need_twopass <= ws_size)
                       && (partPropBytes <= recBytes) && (partDegBytes <= recBytes);

    if (twopass) {
        uint2* recA = (uint2*)pRecA;
        uint2* recB = (uint2*)pRecB;
        float* dinv = (float*)pDinv;
        float2* y0  = (float2*)pY0;
        float2* y1  = (float2*)pY1;
        float2* tx1 = (float2*)pTx1;
        int* histS = (int*)pHist;
        int* histD = (int*)(pHist + histBytes);
        int* baseS = (int*)(pHist + 2 * histBytes);
        int* baseD = (int*)(pHist + 3 * histBytes);
        int* curS  = (int*)(pHist + 4 * histBytes);
        int* curD  = (int*)(pHist + 5 * histBytes);
        float* partDeg  = (float*)pRecB;   // dead until k_sortB writes recB
        float* partProp = (float*)pRecA;   // recA dead after k_sortB

        k_zero_ints<<<(2 * NBC_MAX + BLK - 1) / BLK, BLK, 0, stream>>>(histS, 2 * NBC_MAX);
        k_hist<<<2048, BLK, 0, stream>>>(srcp, dstp, histS, histD, ne, NBC);
        k_scan<<<2, BLK, 0, stream>>>(histS, baseS, curS, histD, baseD, curD, NBC);
        k_sortA<<<NCH, BLK_SS, 0, stream>>>(srcp, dstp, w, curS, recA, ne, NBC, NCH);
        k_degaccA<<<NBC * split, BLK_ACC, 0, stream>>>(recA, baseS, histS, partDeg, split);
        k_degfin<<<nblocks, BLK, 0, stream>>>(partDeg, (const float2*)x, dinv, y0, n, split);
        k_sortB<<<NCH, BLK_SS, 0, stream>>>(recA, baseS, curD, recB, ne, NBC, NCH);
        // A/B: pass 1 = float LDS atomics (control), pass 2 = int fixed-point
        k_propacc<0><<<NBC * split, BLK_ACC, 0, stream>>>(recB, baseD, histD, y0,
                                                          (float2*)partProp, split);
        k_propfin1<<<nblocks, BLK, 0, stream>>>((const float2*)partProp, dinv,
                                                tx1, y1, n, split);
        k_propacc<1><<<NBC * split, BLK_ACC, 0, stream>>>(recB, baseD, histD, y1,
                                                          (float2*)partProp, split);
        k_propfin2<<<nblocks, BLK, 0, stream>>>((const float2*)partProp, dinv,
                                                (const float2*)x, tx1,
                                                Wxz, Wxh, bxz, bhz, bxh, bhh,
                                                (float*)d_out, n, split);
        return;
    }

    // last-resort: global-atomic path
    size_t foff = 0;
    auto falloc = [&](size_t bytes) -> char* {
        char* p = ws + foff;
        foff = (foff + bytes + 255) & ~(size_t)255;
        return p;
    };
    float* deg   = (float*)falloc((size_t)n * sizeof(float));
    float* ftx1  = (float*)falloc((size_t)n * 2 * sizeof(float));
    float* ftx2a = (float*)falloc((size_t)n * 2 * sizeof(float));
    const long long n4 = (long long)(foff / 16);
    k_zero_f4<<<1024, BLK, 0, stream>>>((float4*)ws, n4);
    k_deg_atomic<<<4096, BLK, 0, stream>>>(srcp, dstp, w, deg, ne);
    k_dinv_inplace<<<nblocks, BLK, 0, stream>>>(deg, n);
    k_prop_atomic<<<4096, BLK, 0, stream>>>(srcp, dstp, w, deg,
                                            (const float2*)x, ftx1, ne);
    k_prop_atomic<<<4096, BLK, 0, stream>>>(srcp, dstp, w, deg,
                                            (const float2*)ftx1, ftx2a, ne);
    k_final<<<nblocks, BLK, 0, stream>>>((const float2*)x, (const float2*)ftx1,
                                         (const float2*)ftx2a,
                                         Wxz, Wxh, bxz, bhz, bxh, bhh,
                                         (float*)d_out, n);
}

// Round 15
// 548.270 us; speedup vs baseline: 1.3547x; 1.1678x over previous
//
#include <hip/hip_runtime.h>

// GConvGRU (ChebConv K=3, GRU with H=0) on MI355X.
// H=0 => out = (1 - sigmoid(Cz + bhz)) * tanh(Ch + bhh); Cz/Ch share the
// Chebyshev basis Tx0=x, Tx1=P x, Tx2=2 P Tx1 - x, P = -D^{-1/2} A D^{-1/2}.
// Factorization: P v = -dinv .* (A_w^T (dinv .* v)), so records store raw w.
//
// R14 A/B: float-vs-int LDS atomics identical (177us) -> atomics are native;
// propacc is bound by ~3 per-lane-serialized divergent ops/record (1 TA
// gather + 2 LDS atomics). This round cuts that to 2: both channels + count
// packed into ONE ds_add_u64 (offset-encoded fields, exact fieldwise sums).

static constexpr int BLK = 256;
static constexpr int BLK_SS = 512;      // sort block
static constexpr int BLK_ACC = 512;
static constexpr int NBC_MAX = 512;     // max coarse buckets (n <= 2^19)
static constexpr int BSHIFT = 10;       // 1024 nodes/bucket
static constexpr int BSIZE = 1024;
static constexpr int SCH = 4096;        // records per sort chunk

__device__ __forceinline__ void atomAddF(float* p, float v) {
    unsafeAtomicAdd(p, v);
}

// ---------------- utility ----------------

__global__ void k_zero_ints(int* __restrict__ p, int n)
{
    int i = blockIdx.x * blockDim.x + threadIdx.x;
    if (i < n) p[i] = 0;
}

__global__ void k_zero_f4(float4* __restrict__ p, long long n4)
{
    long long i = (long long)blockIdx.x * blockDim.x + threadIdx.x;
    long long stride = (long long)gridDim.x * blockDim.x;
    for (; i < n4; i += stride) p[i] = make_float4(0.f, 0.f, 0.f, 0.f);
}

// ---------------- histogram + scan ----------------

__global__ void k_hist(const int* __restrict__ srcp, const int* __restrict__ dstp,
                       int* __restrict__ histS, int* __restrict__ histD,
                       long long ne, int NB)
{
    __shared__ int lS[NBC_MAX];
    __shared__ int lD[NBC_MAX];
    for (int b = threadIdx.x; b < NB; b += blockDim.x) { lS[b] = 0; lD[b] = 0; }
    __syncthreads();

    const long long ng = (ne + 3) >> 2;
    const long long stride = (long long)gridDim.x * blockDim.x;
    for (long long g = (long long)blockIdx.x * blockDim.x + threadIdx.x; g < ng; g += stride) {
        const long long e = g << 2;
        if (e + 3 < ne) {
            int4 s4 = *(const int4*)(srcp + e);
            int4 d4 = *(const int4*)(dstp + e);
            atomicAdd(&lS[s4.x >> BSHIFT], 1); atomicAdd(&lS[s4.y >> BSHIFT], 1);
            atomicAdd(&lS[s4.z >> BSHIFT], 1); atomicAdd(&lS[s4.w >> BSHIFT], 1);
            atomicAdd(&lD[d4.x >> BSHIFT], 1); atomicAdd(&lD[d4.y >> BSHIFT], 1);
            atomicAdd(&lD[d4.z >> BSHIFT], 1); atomicAdd(&lD[d4.w >> BSHIFT], 1);
        } else {
            for (long long q = e; q < ne; ++q) {
                atomicAdd(&lS[srcp[q] >> BSHIFT], 1);
                atomicAdd(&lD[dstp[q] >> BSHIFT], 1);
            }
        }
    }
    __syncthreads();
    for (int b = threadIdx.x; b < NB; b += blockDim.x) {
        if (lS[b]) atomicAdd(&histS[b], lS[b]);
        if (lD[b]) atomicAdd(&histD[b], lD[b]);
    }
}

// Exclusive scan: block 0 does S, block 1 does D. NB <= 512, BLK=256.
__global__ void k_scan(const int* __restrict__ histS, int* __restrict__ baseS, int* __restrict__ curS,
                       const int* __restrict__ histD, int* __restrict__ baseD, int* __restrict__ curD,
                       int NB)
{
    const int* hist = (blockIdx.x == 0) ? histS : histD;
    int* base = (blockIdx.x == 0) ? baseS : baseD;
    int* cur  = (blockIdx.x == 0) ? curS  : curD;

    __shared__ int part[BLK];
    int t = threadIdx.x;
    int v0 = (2 * t     < NB) ? hist[2 * t]     : 0;
    int v1 = (2 * t + 1 < NB) ? hist[2 * t + 1] : 0;
    part[t] = v0 + v1;
    __syncthreads();
    for (int off = 1; off < BLK; off <<= 1) {
        int val = (t >= off) ? part[t - off] : 0;
        __syncthreads();
        part[t] += val;
        __syncthreads();
    }
    int run = (t == 0) ? 0 : part[t - 1];
    if (2 * t < NB)     { base[2 * t] = run;          cur[2 * t] = run; }
    if (2 * t + 1 < NB) { base[2 * t + 1] = run + v0; cur[2 * t + 1] = run + v0; }
}

// ---------------- pass A: sort raw edges by src-bucket ----------------
// recA = { dst(19b) | srcLocal(10b)<<19 , w_full } (w=0 for self-loops)
__global__ __launch_bounds__(BLK_SS)
void k_sortA(const int* __restrict__ srcp, const int* __restrict__ dstp,
             const float* __restrict__ w, int* __restrict__ curS,
             uint2* __restrict__ recA, long long ne, int NB, int NCH)
{
    __shared__ uint2 stage[SCH];            // 32 KB
    __shared__ unsigned short slotbkt[SCH]; // 8 KB
    __shared__ int loff[NBC_MAX];
    __shared__ int gdelta[NBC_MAX];
    __shared__ int stmp[BLK_SS];

    const int orig = blockIdx.x;
    const int xcd = orig & 7, idx = orig >> 3;
    const int q8 = NCH >> 3, r8 = NCH & 7;
    const int chunk = (xcd < r8 ? xcd * (q8 + 1) : r8 * (q8 + 1) + (xcd - r8) * q8) + idx;

    const long long cs = (long long)chunk * SCH;
    if (cs >= ne) return;
    const int cnt = (int)(((cs + SCH) < ne) ? SCH : (ne - cs));
    const int t = threadIdx.x;

    for (int b = t; b < NB; b += BLK_SS) loff[b] = 0;
    __syncthreads();

    for (int i = t * 4; i < cnt; i += BLK_SS * 4) {
        if (i + 3 < cnt) {
            int4 k4 = *(const int4*)(srcp + cs + i);
            atomicAdd(&loff[k4.x >> BSHIFT], 1); atomicAdd(&loff[k4.y >> BSHIFT], 1);
            atomicAdd(&loff[k4.z >> BSHIFT], 1); atomicAdd(&loff[k4.w >> BSHIFT], 1);
        } else {
            for (int q = i; q < cnt; ++q)
                atomicAdd(&loff[srcp[cs + q] >> BSHIFT], 1);
        }
    }
    __syncthreads();

    int v = (t < NB) ? loff[t] : 0;
    stmp[t] = v;
    __syncthreads();
    for (int off = 1; off < BLK_SS; off <<= 1) {
        int val = (t >= off) ? stmp[t - off] : 0;
        __syncthreads();
        stmp[t] += val;
        __syncthreads();
    }
    int excl = stmp[t] - v;
    if (t < NB) {
        int g = (v > 0) ? atomicAdd(&curS[t], v) : 0;
        loff[t] = excl;
        gdelta[t] = g - excl;
    }
    __syncthreads();

    for (int i = t * 4; i < cnt; i += BLK_SS * 4) {
        if (i + 3 < cnt) {
            int4 s4 = *(const int4*)(srcp + cs + i);
            int4 d4 = *(const int4*)(dstp + cs + i);
            float4 w4 = *(const float4*)(w + cs + i);
            int ss[4] = {s4.x, s4.y, s4.z, s4.w};
            int dd[4] = {d4.x, d4.y, d4.z, d4.w};
            float wv[4] = {w4.x, w4.y, w4.z, w4.w};
#pragma unroll
            for (int j = 0; j < 4; ++j) {
                float we = (ss[j] == dd[j]) ? 0.0f : wv[j];
                int b = ss[j] >> BSHIFT;
                int pos = atomicAdd(&loff[b], 1);
                stage[pos] = make_uint2(
                    (unsigned)dd[j] | ((unsigned)(ss[j] & (BSIZE - 1)) << 19),
                    __float_as_uint(we));
                slotbkt[pos] = (unsigned short)b;
            }
        } else {
            for (int q = i; q < cnt; ++q) {
                int s = srcp[cs + q], d = dstp[cs + q];
                float we = (s == d) ? 0.0f : w[cs + q];
                int b = s >> BSHIFT;
                int pos = atomicAdd(&loff[b], 1);
                stage[pos] = make_uint2(
                    (unsigned)d | ((unsigned)(s & (BSIZE - 1)) << 19),
                    __float_as_uint(we));
                slotbkt[pos] = (unsigned short)b;
            }
        }
    }
    __syncthreads();

    for (int i = t; i < cnt; i += BLK_SS) {
        int b = slotbkt[i];
        recA[(long long)(i + gdelta[b])] = stage[i];
    }
}

// ---------------- pass B: re-sort recA by dst-bucket ----------------
__global__ __launch_bounds__(BLK_SS)
void k_sortB(const uint2* __restrict__ recA, const int* __restrict__ baseS,
             int* __restrict__ curD, uint2* __restrict__ recB,
             long long ne, int NB, int NCH)
{
    __shared__ uint2 stage[SCH];
    __shared__ unsigned short slotbkt[SCH];
    __shared__ int loff[NBC_MAX];
    __shared__ int gdelta[NBC_MAX];
    __shared__ int stmp[BLK_SS];
    __shared__ int lbaseS[NBC_MAX];

    const int orig = blockIdx.x;
    const int xcd = orig & 7, idx = orig >> 3;
    const int q8 = NCH >> 3, r8 = NCH & 7;
    const int chunk = (xcd < r8 ? xcd * (q8 + 1) : r8 * (q8 + 1) + (xcd - r8) * q8) + idx;

    const long long cs = (long long)chunk * SCH;
    if (cs >= ne) return;
    const int cnt = (int)(((cs + SCH) < ne) ? SCH : (ne - cs));
    const int t = threadIdx.x;

    for (int b = t; b < NB; b += BLK_SS) { loff[b] = 0; lbaseS[b] = baseS[b]; }
    __syncthreads();

    for (int i = t * 2; i < cnt; i += BLK_SS * 2) {
        if (i + 1 < cnt) {
            uint4 two = *(const uint4*)(recA + cs + i);
            atomicAdd(&loff[(two.x & 0x7FFFFu) >> BSHIFT], 1);
            atomicAdd(&loff[(two.z & 0x7FFFFu) >> BSHIFT], 1);
        } else {
            uint2 one = recA[cs + i];
            atomicAdd(&loff[(one.x & 0x7FFFFu) >> BSHIFT], 1);
        }
    }
    __syncthreads();

    int v = (t < NB) ? loff[t] : 0;
    stmp[t] = v;
    __syncthreads();
    for (int off = 1; off < BLK_SS; off <<= 1) {
        int val = (t >= off) ? stmp[t - off] : 0;
        __syncthreads();
        stmp[t] += val;
        __syncthreads();
    }
    int excl = stmp[t] - v;
    if (t < NB) {
        int g = (v > 0) ? atomicAdd(&curD[t], v) : 0;
        loff[t] = excl;
        gdelta[t] = g - excl;
    }
    __syncthreads();

    for (int i = t; i < cnt; i += BLK_SS) {
        uint2 rec = recA[cs + i];
        int p;
        {
            long long gp = cs + i;
            int lo = 0, hi = NB;
            while (hi - lo > 1) {
                int mid = (lo + hi) >> 1;
                if ((long long)lbaseS[mid] <= gp) lo = mid; else hi = mid;
            }
            p = lo;
        }
        unsigned dstF = rec.x & 0x7FFFFu;
        unsigned srcL = (rec.x >> 19) & (BSIZE - 1u);
        unsigned srcF = ((unsigned)p << BSHIFT) | srcL;
        int b = (int)(dstF >> BSHIFT);
        int pos = atomicAdd(&loff[b], 1);
        stage[pos] = make_uint2(srcF | ((dstF & (BSIZE - 1u)) << 19), rec.y);
        slotbkt[pos] = (unsigned short)b;
    }
    __syncthreads();

    for (int i = t; i < cnt; i += BLK_SS) {
        int b = slotbkt[i];
        recB[(long long)(i + gdelta[b])] = stage[i];
    }
}

// ---------------- accumulate + combine ----------------

__global__ __launch_bounds__(BLK_ACC)
void k_degaccA(const uint2* __restrict__ recs, const int* __restrict__ base,
               const int* __restrict__ hist, float* __restrict__ part, int split)
{
    __shared__ float lacc[BSIZE];
    const int b = blockIdx.x / split, sp = blockIdx.x % split;
    for (int i = threadIdx.x; i < BSIZE; i += blockDim.x) lacc[i] = 0.0f;
    __syncthreads();
    const int cnt = hist[b];
    const uint2* rp = recs + base[b];
    const int i0 = (int)((long long)cnt * sp / split);
    const int i1 = (int)((long long)cnt * (sp + 1) / split);
    for (int r = i0 + threadIdx.x; r < i1; r += blockDim.x) {
        uint2 rec = rp[r];
        atomicAdd(&lacc[(rec.x >> 19) & (BSIZE - 1u)], __uint_as_float(rec.y));
    }
    __syncthreads();
    float* dst = part + (size_t)(b * split + sp) * BSIZE;
    for (int i = threadIdx.x; i < BSIZE; i += blockDim.x)
        __builtin_nontemporal_store(lacc[i], dst + i);
}

__global__ void k_degfin(const float* __restrict__ part, const float2* __restrict__ x,
                         float* __restrict__ dinv, float2* __restrict__ y0,
                         int n, int split)
{
    int node = blockIdx.x * blockDim.x + threadIdx.x;
    if (node >= n) return;
    int b = node >> BSHIFT, loc = node & (BSIZE - 1);
    float dg = 0.0f;
    for (int sp = 0; sp < split; ++sp)
        dg += part[(size_t)(b * split + sp) * BSIZE + loc];
    float di = (dg > 0.0f) ? rsqrtf(dg) : 0.0f;
    dinv[node] = di;
    float2 xv = x[node];
    y0[node] = make_float2(di * xv.x, di * xv.y);
}

// prop partial: ONE packed ds_add_u64 per record (x[0:25)|y[25:50)|cnt[50:64),
// offset-encoded so all fields accumulate positive; exact fieldwise sums.
// scale 2^12, offset 2^17: |val|<=32 ok; <=128 adds/slot (observed <~20).
__global__ __launch_bounds__(BLK_ACC)
void k_propacc(const uint2* __restrict__ recs, const int* __restrict__ base,
               const int* __restrict__ hist, const float2* __restrict__ yin,
               float2* __restrict__ part, int split)
{
    __shared__ unsigned long long acc64[BSIZE];   // 8 KB
    const float S = 4096.0f;               // 2^12
    const float INVS = 1.0f / 4096.0f;
    const int OFF = 131072;                // 2^17
    const unsigned long long M25 = (1ULL << 25) - 1;

    const int b = blockIdx.x / split, sp = blockIdx.x % split;
    for (int i = threadIdx.x; i < BSIZE; i += blockDim.x) acc64[i] = 0ULL;
    __syncthreads();
    const int cnt = hist[b];
    const uint2* rp = recs + base[b];
    const int i0 = (int)((long long)cnt * sp / split);
    const int i1 = (int)((long long)cnt * (sp + 1) / split);
    for (int r = i0 + threadIdx.x; r < i1; r += blockDim.x) {
        uint2 rec = rp[r];
        int s  = (int)(rec.x & 0x7FFFFu);
        int dl = (int)(rec.x >> 19);
        float wv = __uint_as_float(rec.y);
        float2 yv = yin[s];
        int xf = __float2int_rn(wv * yv.x * S) + OFF;
        int yf = __float2int_rn(wv * yv.y * S) + OFF;
        unsigned long long val = (unsigned long long)(unsigned)xf
                               | ((unsigned long long)(unsigned)yf << 25)
                               | (1ULL << 50);
        atomicAdd(&acc64[dl], val);
    }
    __syncthreads();
    unsigned long long* dst =
        (unsigned long long*)(part + (size_t)(b * split + sp) * BSIZE);
    for (int i = threadIdx.x; i < BSIZE; i += blockDim.x) {
        unsigned long long v = acc64[i];
        long long k  = (long long)(v >> 50);
        long long xr = (long long)(v & M25) - k * OFF;
        long long yr = (long long)((v >> 25) & M25) - k * OFF;
        float fx = (float)xr * INVS;
        float fy = (float)yr * INVS;
        unsigned long long pk = (unsigned long long)__float_as_uint(fx)
                              | ((unsigned long long)__float_as_uint(fy) << 32);
        __builtin_nontemporal_store(pk, dst + i);
    }
}

__global__ void k_propfin1(const float2* __restrict__ part, const float* __restrict__ dinv,
                           float2* __restrict__ tx1, float2* __restrict__ y1,
                           int n, int split)
{
    int node = blockIdx.x * blockDim.x + threadIdx.x;
    if (node >= n) return;
    int b = node >> BSHIFT, loc = node & (BSIZE - 1);
    float sx = 0.0f, sy = 0.0f;
    for (int sp = 0; sp < split; ++sp) {
        float2 v = part[(size_t)(b * split + sp) * BSIZE + loc];
        sx += v.x; sy += v.y;
    }
    float di = dinv[node];
    float ox = -di * sx, oy = -di * sy;
    tx1[node] = make_float2(ox, oy);
    y1[node] = make_float2(di * ox, di * oy);
}

__global__ void k_propfin2(const float2* __restrict__ part, const float* __restrict__ dinv,
                           const float2* __restrict__ x, const float2* __restrict__ tx1,
                           const float* __restrict__ Wxz, const float* __restrict__ Wxh,
                           const float* __restrict__ bxz, const float* __restrict__ bhz,
                           const float* __restrict__ bxh, const float* __restrict__ bhh,
                           float* __restrict__ out, int n, int split)
{
    int node = blockIdx.x * blockDim.x + threadIdx.x;
    if (node >= n) return;
    int b = node >> BSHIFT, loc = node & (BSIZE - 1);
    float sx = 0.0f, sy = 0.0f;
    for (int sp = 0; sp < split; ++sp) {
        float2 v = part[(size_t)(b * split + sp) * BSIZE + loc];
        sx += v.x; sy += v.y;
    }
    float di = dinv[node];
    float2 t0 = x[node];
    float2 t1 = tx1[node];
    float t2x = 2.0f * (-di * sx) - t0.x;
    float t2y = 2.0f * (-di * sy) - t0.y;
    float z = t0.x * Wxz[0] + t0.y * Wxz[1]
            + t1.x * Wxz[2] + t1.y * Wxz[3]
            + t2x  * Wxz[4] + t2y  * Wxz[5] + bxz[0] + bhz[0];
    float h = t0.x * Wxh[0] + t0.y * Wxh[1]
            + t1.x * Wxh[2] + t1.y * Wxh[3]
            + t2x  * Wxh[4] + t2y  * Wxh[5] + bxh[0] + bhh[0];
    float zs = 1.0f / (1.0f + expf(-z));
    float ht = tanhf(h);
    out[node] = (1.0f - zs) * ht;
}

// ---------------- atomic fallback ----------------

__global__ void k_deg_atomic(const int* __restrict__ srcp, const int* __restrict__ dstp,
                             const float* __restrict__ w, float* __restrict__ deg,
                             long long ne)
{
    const long long ng = (ne + 3) >> 2;
    const long long stride = (long long)gridDim.x * blockDim.x;
    for (long long g = (long long)blockIdx.x * blockDim.x + threadIdx.x; g < ng; g += stride) {
        const long long e = g << 2;
        if (e + 3 < ne) {
            int4 s4 = *(const int4*)(srcp + e);
            int4 d4 = *(const int4*)(dstp + e);
            float4 w4 = *(const float4*)(w + e);
            if (s4.x != d4.x) atomAddF(&deg[s4.x], w4.x);
            if (s4.y != d4.y) atomAddF(&deg[s4.y], w4.y);
            if (s4.z != d4.z) atomAddF(&deg[s4.z], w4.z);
            if (s4.w != d4.w) atomAddF(&deg[s4.w], w4.w);
        } else {
            for (long long q = e; q < ne; ++q) {
                int s = srcp[q], d = dstp[q];
                if (s != d) atomAddF(&deg[s], w[q]);
            }
        }
    }
}

__global__ void k_dinv_inplace(float* __restrict__ deg, int n)
{
    int i = blockIdx.x * blockDim.x + threadIdx.x;
    if (i < n) {
        float d = deg[i];
        deg[i] = (d > 0.0f) ? rsqrtf(d) : 0.0f;
    }
}

__global__ void k_prop_atomic(const int* __restrict__ srcp, const int* __restrict__ dstp,
                              const float* __restrict__ w, const float* __restrict__ dinv,
                              const float2* __restrict__ xin, float* __restrict__ acc,
                              long long ne)
{
    const long long ng = (ne + 3) >> 2;
    const long long stride = (long long)gridDim.x * blockDim.x;
    for (long long g = (long long)blockIdx.x * blockDim.x + threadIdx.x; g < ng; g += stride) {
        const long long e = g << 2;
        if (e + 3 < ne) {
            int4 s4 = *(const int4*)(srcp + e);
            int4 d4 = *(const int4*)(dstp + e);
            float4 w4 = *(const float4*)(w + e);
            int s[4] = {s4.x, s4.y, s4.z, s4.w};
            int d[4] = {d4.x, d4.y, d4.z, d4.w};
            float wv[4] = {w4.x, w4.y, w4.z, w4.w};
#pragma unroll
            for (int j = 0; j < 4; ++j) {
                float wn = (s[j] != d[j]) ? -(dinv[s[j]] * wv[j] * dinv[d[j]]) : 0.0f;
                float2 xv = xin[s[j]];
                atomAddF(&acc[2 * d[j] + 0], wn * xv.x);
                atomAddF(&acc[2 * d[j] + 1], wn * xv.y);
            }
        } else {
            for (long long q = e; q < ne; ++q) {
                int ss = srcp[q], dd = dstp[q];
                float wn = (ss != dd) ? -(dinv[ss] * w[q] * dinv[dd]) : 0.0f;
                float2 xv = xin[ss];
                atomAddF(&acc[2 * dd + 0], wn * xv.x);
                atomAddF(&acc[2 * dd + 1], wn * xv.y);
            }
        }
    }
}

__global__ void k_final(const float2* __restrict__ x, const float2* __restrict__ tx1,
                        const float2* __restrict__ tx2a,
                        const float* __restrict__ Wxz, const float* __restrict__ Wxh,
                        const float* __restrict__ bxz, const float* __restrict__ bhz,
                        const float* __restrict__ bxh, const float* __restrict__ bhh,
                        float* __restrict__ out, int n)
{
    int i = blockIdx.x * blockDim.x + threadIdx.x;
    if (i >= n) return;
    float2 t0 = x[i];
    float2 t1 = tx1[i];
    float2 ta = tx2a[i];
    float t2x = 2.0f * ta.x - t0.x;
    float t2y = 2.0f * ta.y - t0.y;
    float z = t0.x * Wxz[0] + t0.y * Wxz[1]
            + t1.x * Wxz[2] + t1.y * Wxz[3]
            + t2x  * Wxz[4] + t2y  * Wxz[5] + bxz[0] + bhz[0];
    float h = t0.x * Wxh[0] + t0.y * Wxh[1]
            + t1.x * Wxh[2] + t1.y * Wxh[3]
            + t2x  * Wxh[4] + t2y  * Wxh[5] + bxh[0] + bhh[0];
    float zs = 1.0f / (1.0f + expf(-z));
    float ht = tanhf(h);
    out[i] = (1.0f - zs) * ht;
}

// ---------------- launch ----------------

extern "C" void kernel_launch(void* const* d_in, const int* in_sizes, int n_in,
                              void* d_out, int out_size, void* d_ws, size_t ws_size,
                              hipStream_t stream)
{
    const float* x   = (const float*)d_in[0];
    const int*   ei  = (const int*)d_in[1];
    const float* w   = (const float*)d_in[2];
    const float* Wxz = (const float*)d_in[3];
    const float* Wxh = (const float*)d_in[5];
    const float* bxz = (const float*)d_in[9];
    const float* bhz = (const float*)d_in[10];
    const float* bxh = (const float*)d_in[13];
    const float* bhh = (const float*)d_in[14];

    const int n = in_sizes[0] / 2;
    const long long ne = in_sizes[2];
    const int* srcp = ei;
    const int* dstp = ei + ne;
    const int nblocks = (n + BLK - 1) / BLK;
    const int NBC = (n + BSIZE - 1) >> BSHIFT;
    const int NCH = (int)((ne + SCH - 1) / SCH);
    char* ws = (char*)d_ws;

    const bool nodes_ok = (n <= (1 << 19)) && (NBC <= NBC_MAX);
    const int split = 8;

    auto align256 = [](size_t v) { return (v + 255) & ~(size_t)255; };
    const size_t recBytes  = align256((size_t)ne * 8);
    const size_t dinvBytes = align256((size_t)n * 4);
    const size_t vecBytes  = align256((size_t)n * 8);
    const size_t histBytes = align256((size_t)NBC_MAX * 4);
    const size_t partPropBytes = (size_t)NBC * split * BSIZE * 8;
    const size_t partDegBytes  = (size_t)NBC * split * BSIZE * 4;

    size_t off = 0;
    char* pRecA = ws + off; off += recBytes;
    char* pRecB = ws + off; off += recBytes;
    char* pDinv = ws + off; off += dinvBytes;
    char* pY0   = ws + off; off += vecBytes;
    char* pY1   = ws + off; off += vecBytes;
    char* pTx1  = ws + off; off += vecBytes;
    char* pHist = ws + off; off += 6 * histBytes;
    const size_t need_twopass = off;
    const bool twopass = nodes_ok && (need_twopass <= ws_size)
                       && (partPropBytes <= recBytes) && (partDegBytes <= recBytes);

    if (twopass) {
        uint2* recA = (uint2*)pRecA;
        uint2* recB = (uint2*)pRecB;
        float* dinv = (float*)pDinv;
        float2* y0  = (float2*)pY0;
        float2* y1  = (float2*)pY1;
        float2* tx1 = (float2*)pTx1;
        int* histS = (int*)pHist;
        int* histD = (int*)(pHist + histBytes);
        int* baseS = (int*)(pHist + 2 * histBytes);
        int* baseD = (int*)(pHist + 3 * histBytes);
        int* curS  = (int*)(pHist + 4 * histBytes);
        int* curD  = (int*)(pHist + 5 * histBytes);
        float* partDeg  = (float*)pRecB;   // dead until k_sortB writes recB
        float* partProp = (float*)pRecA;   // recA dead after k_sortB

        k_zero_ints<<<(2 * NBC_MAX + BLK - 1) / BLK, BLK, 0, stream>>>(histS, 2 * NBC_MAX);
        k_hist<<<2048, BLK, 0, stream>>>(srcp, dstp, histS, histD, ne, NBC);
        k_scan<<<2, BLK, 0, stream>>>(histS, baseS, curS, histD, baseD, curD, NBC);
        k_sortA<<<NCH, BLK_SS, 0, stream>>>(srcp, dstp, w, curS, recA, ne, NBC, NCH);
        k_degaccA<<<NBC * split, BLK_ACC, 0, stream>>>(recA, baseS, histS, partDeg, split);
        k_degfin<<<nblocks, BLK, 0, stream>>>(partDeg, (const float2*)x, dinv, y0, n, split);
        k_sortB<<<NCH, BLK_SS, 0, stream>>>(recA, baseS, curD, recB, ne, NBC, NCH);
        k_propacc<<<NBC * split, BLK_ACC, 0, stream>>>(recB, baseD, histD, y0,
                                                       (float2*)partProp, split);
        k_propfin1<<<nblocks, BLK, 0, stream>>>((const float2*)partProp, dinv,
                                                tx1, y1, n, split);
        k_propacc<<<NBC * split, BLK_ACC, 0, stream>>>(recB, baseD, histD, y1,
                                                       (float2*)partProp, split);
        k_propfin2<<<nblocks, BLK, 0, stream>>>((const float2*)partProp, dinv,
                                                (const float2*)x, tx1,
                                                Wxz, Wxh, bxz, bhz, bxh, bhh,
                                                (float*)d_out, n, split);
        return;
    }

    // last-resort: global-atomic path
    size_t foff = 0;
    auto falloc = [&](size_t bytes) -> char* {
        char* p = ws + foff;
        foff = (foff + bytes + 255) & ~(size_t)255;
        return p;
    };
    float* deg   = (float*)falloc((size_t)n * sizeof(float));
    float* ftx1  = (float*)falloc((size_t)n * 2 * sizeof(float));
    float* ftx2a = (float*)falloc((size_t)n * 2 * sizeof(float));
    const long long n4 = (long long)(foff / 16);
    k_zero_f4<<<1024, BLK, 0, stream>>>((float4*)ws, n4);
    k_deg_atomic<<<4096, BLK, 0, stream>>>(srcp, dstp, w, deg, ne);
    k_dinv_inplace<<<nblocks, BLK, 0, stream>>>(deg, n);
    k_prop_atomic<<<4096, BLK, 0, stream>>>(srcp, dstp, w, deg,
                                            (const float2*)x, ftx1, ne);
    k_prop_atomic<<<4096, BLK, 0, stream>>>(srcp, dstp, w, deg,
                                            (const float2*)ftx1, ftx2a, ne);
    k_final<<<nblocks, BLK, 0, stream>>>((const float2*)x, (const float2*)ftx1,
                                         (const float2*)ftx2a,
                                         Wxz, Wxh, bxz, bhz, bxh, bhh,
                                         (float*)d_out, n);
}

// Round 16
// 547.390 us; speedup vs baseline: 1.3569x; 1.0016x over previous
//
#include <hip/hip_runtime.h>

// GConvGRU (ChebConv K=3, GRU with H=0) on MI355X.
// H=0 => out = (1 - sigmoid(Cz + bhz)) * tanh(Ch + bhh); Cz/Ch share the
// Chebyshev basis Tx0=x, Tx1=P x, Tx2=2 P Tx1 - x, P = -D^{-1/2} A D^{-1/2}.
// Factorization: P v = -dinv .* (A_w^T (dinv .* v)), so records store raw w.
//
// R15: packed ds_add_u64 dropped propacc below sortA/sortB (119/117us).
// This round: sortB's per-record 9-step LDS bsearch replaced by monotone
// linear advance (record positions increase per thread, recA bucket-sorted
// => src bucket non-decreasing); propacc/degacc go 2-wide per iteration.

static constexpr int BLK = 256;
static constexpr int BLK_SS = 512;      // sort block
static constexpr int BLK_ACC = 512;
static constexpr int NBC_MAX = 512;     // max coarse buckets (n <= 2^19)
static constexpr int BSHIFT = 10;       // 1024 nodes/bucket
static constexpr int BSIZE = 1024;
static constexpr int SCH = 4096;        // records per sort chunk

__device__ __forceinline__ void atomAddF(float* p, float v) {
    unsafeAtomicAdd(p, v);
}

// ---------------- utility ----------------

__global__ void k_zero_ints(int* __restrict__ p, int n)
{
    int i = blockIdx.x * blockDim.x + threadIdx.x;
    if (i < n) p[i] = 0;
}

__global__ void k_zero_f4(float4* __restrict__ p, long long n4)
{
    long long i = (long long)blockIdx.x * blockDim.x + threadIdx.x;
    long long stride = (long long)gridDim.x * blockDim.x;
    for (; i < n4; i += stride) p[i] = make_float4(0.f, 0.f, 0.f, 0.f);
}

// ---------------- histogram + scan ----------------

__global__ void k_hist(const int* __restrict__ srcp, const int* __restrict__ dstp,
                       int* __restrict__ histS, int* __restrict__ histD,
                       long long ne, int NB)
{
    __shared__ int lS[NBC_MAX];
    __shared__ int lD[NBC_MAX];
    for (int b = threadIdx.x; b < NB; b += blockDim.x) { lS[b] = 0; lD[b] = 0; }
    __syncthreads();

    const long long ng = (ne + 3) >> 2;
    const long long stride = (long long)gridDim.x * blockDim.x;
    for (long long g = (long long)blockIdx.x * blockDim.x + threadIdx.x; g < ng; g += stride) {
        const long long e = g << 2;
        if (e + 3 < ne) {
            int4 s4 = *(const int4*)(srcp + e);
            int4 d4 = *(const int4*)(dstp + e);
            atomicAdd(&lS[s4.x >> BSHIFT], 1); atomicAdd(&lS[s4.y >> BSHIFT], 1);
            atomicAdd(&lS[s4.z >> BSHIFT], 1); atomicAdd(&lS[s4.w >> BSHIFT], 1);
            atomicAdd(&lD[d4.x >> BSHIFT], 1); atomicAdd(&lD[d4.y >> BSHIFT], 1);
            atomicAdd(&lD[d4.z >> BSHIFT], 1); atomicAdd(&lD[d4.w >> BSHIFT], 1);
        } else {
            for (long long q = e; q < ne; ++q) {
                atomicAdd(&lS[srcp[q] >> BSHIFT], 1);
                atomicAdd(&lD[dstp[q] >> BSHIFT], 1);
            }
        }
    }
    __syncthreads();
    for (int b = threadIdx.x; b < NB; b += blockDim.x) {
        if (lS[b]) atomicAdd(&histS[b], lS[b]);
        if (lD[b]) atomicAdd(&histD[b], lD[b]);
    }
}

// Exclusive scan: block 0 does S, block 1 does D. NB <= 512, BLK=256.
__global__ void k_scan(const int* __restrict__ histS, int* __restrict__ baseS, int* __restrict__ curS,
                       const int* __restrict__ histD, int* __restrict__ baseD, int* __restrict__ curD,
                       int NB)
{
    const int* hist = (blockIdx.x == 0) ? histS : histD;
    int* base = (blockIdx.x == 0) ? baseS : baseD;
    int* cur  = (blockIdx.x == 0) ? curS  : curD;

    __shared__ int part[BLK];
    int t = threadIdx.x;
    int v0 = (2 * t     < NB) ? hist[2 * t]     : 0;
    int v1 = (2 * t + 1 < NB) ? hist[2 * t + 1] : 0;
    part[t] = v0 + v1;
    __syncthreads();
    for (int off = 1; off < BLK; off <<= 1) {
        int val = (t >= off) ? part[t - off] : 0;
        __syncthreads();
        part[t] += val;
        __syncthreads();
    }
    int run = (t == 0) ? 0 : part[t - 1];
    if (2 * t < NB)     { base[2 * t] = run;          cur[2 * t] = run; }
    if (2 * t + 1 < NB) { base[2 * t + 1] = run + v0; cur[2 * t + 1] = run + v0; }
}

// ---------------- pass A: sort raw edges by src-bucket ----------------
// recA = { dst(19b) | srcLocal(10b)<<19 , w_full } (w=0 for self-loops)
__global__ __launch_bounds__(BLK_SS)
void k_sortA(const int* __restrict__ srcp, const int* __restrict__ dstp,
             const float* __restrict__ w, int* __restrict__ curS,
             uint2* __restrict__ recA, long long ne, int NB, int NCH)
{
    __shared__ uint2 stage[SCH];            // 32 KB
    __shared__ unsigned short slotbkt[SCH]; // 8 KB
    __shared__ int loff[NBC_MAX];
    __shared__ int gdelta[NBC_MAX];
    __shared__ int stmp[BLK_SS];

    const int orig = blockIdx.x;
    const int xcd = orig & 7, idx = orig >> 3;
    const int q8 = NCH >> 3, r8 = NCH & 7;
    const int chunk = (xcd < r8 ? xcd * (q8 + 1) : r8 * (q8 + 1) + (xcd - r8) * q8) + idx;

    const long long cs = (long long)chunk * SCH;
    if (cs >= ne) return;
    const int cnt = (int)(((cs + SCH) < ne) ? SCH : (ne - cs));
    const int t = threadIdx.x;

    for (int b = t; b < NB; b += BLK_SS) loff[b] = 0;
    __syncthreads();

    for (int i = t * 4; i < cnt; i += BLK_SS * 4) {
        if (i + 3 < cnt) {
            int4 k4 = *(const int4*)(srcp + cs + i);
            atomicAdd(&loff[k4.x >> BSHIFT], 1); atomicAdd(&loff[k4.y >> BSHIFT], 1);
            atomicAdd(&loff[k4.z >> BSHIFT], 1); atomicAdd(&loff[k4.w >> BSHIFT], 1);
        } else {
            for (int q = i; q < cnt; ++q)
                atomicAdd(&loff[srcp[cs + q] >> BSHIFT], 1);
        }
    }
    __syncthreads();

    int v = (t < NB) ? loff[t] : 0;
    stmp[t] = v;
    __syncthreads();
    for (int off = 1; off < BLK_SS; off <<= 1) {
        int val = (t >= off) ? stmp[t - off] : 0;
        __syncthreads();
        stmp[t] += val;
        __syncthreads();
    }
    int excl = stmp[t] - v;
    if (t < NB) {
        int g = (v > 0) ? atomicAdd(&curS[t], v) : 0;
        loff[t] = excl;
        gdelta[t] = g - excl;
    }
    __syncthreads();

    for (int i = t * 4; i < cnt; i += BLK_SS * 4) {
        if (i + 3 < cnt) {
            int4 s4 = *(const int4*)(srcp + cs + i);
            int4 d4 = *(const int4*)(dstp + cs + i);
            float4 w4 = *(const float4*)(w + cs + i);
            int ss[4] = {s4.x, s4.y, s4.z, s4.w};
            int dd[4] = {d4.x, d4.y, d4.z, d4.w};
            float wv[4] = {w4.x, w4.y, w4.z, w4.w};
#pragma unroll
            for (int j = 0; j < 4; ++j) {
                float we = (ss[j] == dd[j]) ? 0.0f : wv[j];
                int b = ss[j] >> BSHIFT;
                int pos = atomicAdd(&loff[b], 1);
                stage[pos] = make_uint2(
                    (unsigned)dd[j] | ((unsigned)(ss[j] & (BSIZE - 1)) << 19),
                    __float_as_uint(we));
                slotbkt[pos] = (unsigned short)b;
            }
        } else {
            for (int q = i; q < cnt; ++q) {
                int s = srcp[cs + q], d = dstp[cs + q];
                float we = (s == d) ? 0.0f : w[cs + q];
                int b = s >> BSHIFT;
                int pos = atomicAdd(&loff[b], 1);
                stage[pos] = make_uint2(
                    (unsigned)d | ((unsigned)(s & (BSIZE - 1)) << 19),
                    __float_as_uint(we));
                slotbkt[pos] = (unsigned short)b;
            }
        }
    }
    __syncthreads();

    for (int i = t; i < cnt; i += BLK_SS) {
        int b = slotbkt[i];
        recA[(long long)(i + gdelta[b])] = stage[i];
    }
}

// ---------------- pass B: re-sort recA by dst-bucket ----------------
// srcFull reconstructed from record position; monotone advance replaces
// the per-record binary search (positions increase per thread; recA is
// bucket-sorted, so the src bucket is non-decreasing along the sequence).
__global__ __launch_bounds__(BLK_SS)
void k_sortB(const uint2* __restrict__ recA, const int* __restrict__ baseS,
             int* __restrict__ curD, uint2* __restrict__ recB,
             long long ne, int NB, int NCH)
{
    __shared__ uint2 stage[SCH];
    __shared__ unsigned short slotbkt[SCH];
    __shared__ int loff[NBC_MAX];
    __shared__ int gdelta[NBC_MAX];
    __shared__ int stmp[BLK_SS];
    __shared__ int lbaseS[NBC_MAX];

    const int orig = blockIdx.x;
    const int xcd = orig & 7, idx = orig >> 3;
    const int q8 = NCH >> 3, r8 = NCH & 7;
    const int chunk = (xcd < r8 ? xcd * (q8 + 1) : r8 * (q8 + 1) + (xcd - r8) * q8) + idx;

    const long long cs = (long long)chunk * SCH;
    if (cs >= ne) return;
    const int cnt = (int)(((cs + SCH) < ne) ? SCH : (ne - cs));
    const int t = threadIdx.x;

    for (int b = t; b < NB; b += BLK_SS) { loff[b] = 0; lbaseS[b] = baseS[b]; }
    __syncthreads();

    for (int i = t * 2; i < cnt; i += BLK_SS * 2) {
        if (i + 1 < cnt) {
            uint4 two = *(const uint4*)(recA + cs + i);
            atomicAdd(&loff[(two.x & 0x7FFFFu) >> BSHIFT], 1);
            atomicAdd(&loff[(two.z & 0x7FFFFu) >> BSHIFT], 1);
        } else {
            uint2 one = recA[cs + i];
            atomicAdd(&loff[(one.x & 0x7FFFFu) >> BSHIFT], 1);
        }
    }
    __syncthreads();

    int v = (t < NB) ? loff[t] : 0;
    stmp[t] = v;
    __syncthreads();
    for (int off = 1; off < BLK_SS; off <<= 1) {
        int val = (t >= off) ? stmp[t - off] : 0;
        __syncthreads();
        stmp[t] += val;
        __syncthreads();
    }
    int excl = stmp[t] - v;
    if (t < NB) {
        int g = (v > 0) ? atomicAdd(&curD[t], v) : 0;
        loff[t] = excl;
        gdelta[t] = g - excl;
    }
    __syncthreads();

    // place pass: initial bsearch once, then monotone linear advance.
    int lo = 0;
    if (t < cnt) {
        long long gp = cs + t;
        int hi = NB;
        while (hi - lo > 1) {
            int mid = (lo + hi) >> 1;
            if ((long long)lbaseS[mid] <= gp) lo = mid; else hi = mid;
        }
    }
    for (int i = t; i < cnt; i += BLK_SS) {
        long long gp = cs + i;
        while (lo + 1 < NB && (long long)lbaseS[lo + 1] <= gp) ++lo;
        uint2 rec = recA[cs + i];
        unsigned dstF = rec.x & 0x7FFFFu;
        unsigned srcL = (rec.x >> 19) & (BSIZE - 1u);
        unsigned srcF = ((unsigned)lo << BSHIFT) | srcL;
        int b = (int)(dstF >> BSHIFT);
        int pos = atomicAdd(&loff[b], 1);
        stage[pos] = make_uint2(srcF | ((dstF & (BSIZE - 1u)) << 19), rec.y);
        slotbkt[pos] = (unsigned short)b;
    }
    __syncthreads();

    for (int i = t; i < cnt; i += BLK_SS) {
        int b = slotbkt[i];
        recB[(long long)(i + gdelta[b])] = stage[i];
    }
}

// ---------------- accumulate + combine ----------------

__global__ __launch_bounds__(BLK_ACC)
void k_degaccA(const uint2* __restrict__ recs, const int* __restrict__ base,
               const int* __restrict__ hist, float* __restrict__ part, int split)
{
    __shared__ float lacc[BSIZE];
    const int b = blockIdx.x / split, sp = blockIdx.x % split;
    for (int i = threadIdx.x; i < BSIZE; i += blockDim.x) lacc[i] = 0.0f;
    __syncthreads();
    const int cnt = hist[b];
    const uint2* rp = recs + base[b];
    const int i0 = (int)((long long)cnt * sp / split);
    const int i1 = (int)((long long)cnt * (sp + 1) / split);
    int r = i0 + threadIdx.x;
    for (; r + BLK_ACC < i1; r += 2 * BLK_ACC) {
        uint2 ra = rp[r];
        uint2 rb = rp[r + BLK_ACC];
        atomicAdd(&lacc[(ra.x >> 19) & (BSIZE - 1u)], __uint_as_float(ra.y));
        atomicAdd(&lacc[(rb.x >> 19) & (BSIZE - 1u)], __uint_as_float(rb.y));
    }
    for (; r < i1; r += BLK_ACC) {
        uint2 rec = rp[r];
        atomicAdd(&lacc[(rec.x >> 19) & (BSIZE - 1u)], __uint_as_float(rec.y));
    }
    __syncthreads();
    float* dst = part + (size_t)(b * split + sp) * BSIZE;
    for (int i = threadIdx.x; i < BSIZE; i += blockDim.x)
        __builtin_nontemporal_store(lacc[i], dst + i);
}

__global__ void k_degfin(const float* __restrict__ part, const float2* __restrict__ x,
                         float* __restrict__ dinv, float2* __restrict__ y0,
                         int n, int split)
{
    int node = blockIdx.x * blockDim.x + threadIdx.x;
    if (node >= n) return;
    int b = node >> BSHIFT, loc = node & (BSIZE - 1);
    float dg = 0.0f;
    for (int sp = 0; sp < split; ++sp)
        dg += part[(size_t)(b * split + sp) * BSIZE + loc];
    float di = (dg > 0.0f) ? rsqrtf(dg) : 0.0f;
    dinv[node] = di;
    float2 xv = x[node];
    y0[node] = make_float2(di * xv.x, di * xv.y);
}

// prop partial: ONE packed ds_add_u64 per record (x[0:25)|y[25:50)|cnt[50:64)),
// offset-encoded, exact fieldwise sums; 2 records per loop iteration.
__global__ __launch_bounds__(BLK_ACC)
void k_propacc(const uint2* __restrict__ recs, const int* __restrict__ base,
               const int* __restrict__ hist, const float2* __restrict__ yin,
               float2* __restrict__ part, int split)
{
    __shared__ unsigned long long acc64[BSIZE];   // 8 KB
    const float S = 4096.0f;               // 2^12
    const float INVS = 1.0f / 4096.0f;
    const int OFF = 131072;                // 2^17
    const unsigned long long M25 = (1ULL << 25) - 1;

    const int b = blockIdx.x / split, sp = blockIdx.x % split;
    for (int i = threadIdx.x; i < BSIZE; i += blockDim.x) acc64[i] = 0ULL;
    __syncthreads();
    const int cnt = hist[b];
    const uint2* rp = recs + base[b];
    const int i0 = (int)((long long)cnt * sp / split);
    const int i1 = (int)((long long)cnt * (sp + 1) / split);
    int r = i0 + threadIdx.x;
    for (; r + BLK_ACC < i1; r += 2 * BLK_ACC) {
        uint2 ra = rp[r];
        uint2 rb = rp[r + BLK_ACC];
        float2 ya = yin[ra.x & 0x7FFFFu];
        float2 yb = yin[rb.x & 0x7FFFFu];
        float wa = __uint_as_float(ra.y);
        float wb = __uint_as_float(rb.y);
        int xa = __float2int_rn(wa * ya.x * S) + OFF;
        int yaq = __float2int_rn(wa * ya.y * S) + OFF;
        int xb = __float2int_rn(wb * yb.x * S) + OFF;
        int ybq = __float2int_rn(wb * yb.y * S) + OFF;
        unsigned long long va = (unsigned long long)(unsigned)xa
                              | ((unsigned long long)(unsigned)yaq << 25)
                              | (1ULL << 50);
        unsigned long long vb = (unsigned long long)(unsigned)xb
                              | ((unsigned long long)(unsigned)ybq << 25)
                              | (1ULL << 50);
        atomicAdd(&acc64[ra.x >> 19], va);
        atomicAdd(&acc64[rb.x >> 19], vb);
    }
    for (; r < i1; r += BLK_ACC) {
        uint2 rec = rp[r];
        float2 yv = yin[rec.x & 0x7FFFFu];
        float wv = __uint_as_float(rec.y);
        int xf = __float2int_rn(wv * yv.x * S) + OFF;
        int yf = __float2int_rn(wv * yv.y * S) + OFF;
        unsigned long long val = (unsigned long long)(unsigned)xf
                               | ((unsigned long long)(unsigned)yf << 25)
                               | (1ULL << 50);
        atomicAdd(&acc64[rec.x >> 19], val);
    }
    __syncthreads();
    unsigned long long* dst =
        (unsigned long long*)(part + (size_t)(b * split + sp) * BSIZE);
    for (int i = threadIdx.x; i < BSIZE; i += blockDim.x) {
        unsigned long long v = acc64[i];
        long long k  = (long long)(v >> 50);
        long long xr = (long long)(v & M25) - k * OFF;
        long long yr = (long long)((v >> 25) & M25) - k * OFF;
        float fx = (float)xr * INVS;
        float fy = (float)yr * INVS;
        unsigned long long pk = (unsigned long long)__float_as_uint(fx)
                              | ((unsigned long long)__float_as_uint(fy) << 32);
        __builtin_nontemporal_store(pk, dst + i);
    }
}

__global__ void k_propfin1(const float2* __restrict__ part, const float* __restrict__ dinv,
                           float2* __restrict__ tx1, float2* __restrict__ y1,
                           int n, int split)
{
    int node = blockIdx.x * blockDim.x + threadIdx.x;
    if (node >= n) return;
    int b = node >> BSHIFT, loc = node & (BSIZE - 1);
    float sx = 0.0f, sy = 0.0f;
    for (int sp = 0; sp < split; ++sp) {
        float2 v = part[(size_t)(b * split + sp) * BSIZE + loc];
        sx += v.x; sy += v.y;
    }
    float di = dinv[node];
    float ox = -di * sx, oy = -di * sy;
    tx1[node] = make_float2(ox, oy);
    y1[node] = make_float2(di * ox, di * oy);
}

__global__ void k_propfin2(const float2* __restrict__ part, const float* __restrict__ dinv,
                           const float2* __restrict__ x, const float2* __restrict__ tx1,
                           const float* __restrict__ Wxz, const float* __restrict__ Wxh,
                           const float* __restrict__ bxz, const float* __restrict__ bhz,
                           const float* __restrict__ bxh, const float* __restrict__ bhh,
                           float* __restrict__ out, int n, int split)
{
    int node = blockIdx.x * blockDim.x + threadIdx.x;
    if (node >= n) return;
    int b = node >> BSHIFT, loc = node & (BSIZE - 1);
    float sx = 0.0f, sy = 0.0f;
    for (int sp = 0; sp < split; ++sp) {
        float2 v = part[(size_t)(b * split + sp) * BSIZE + loc];
        sx += v.x; sy += v.y;
    }
    float di = dinv[node];
    float2 t0 = x[node];
    float2 t1 = tx1[node];
    float t2x = 2.0f * (-di * sx) - t0.x;
    float t2y = 2.0f * (-di * sy) - t0.y;
    float z = t0.x * Wxz[0] + t0.y * Wxz[1]
            + t1.x * Wxz[2] + t1.y * Wxz[3]
            + t2x  * Wxz[4] + t2y  * Wxz[5] + bxz[0] + bhz[0];
    float h = t0.x * Wxh[0] + t0.y * Wxh[1]
            + t1.x * Wxh[2] + t1.y * Wxh[3]
            + t2x  * Wxh[4] + t2y  * Wxh[5] + bxh[0] + bhh[0];
    float zs = 1.0f / (1.0f + expf(-z));
    float ht = tanhf(h);
    out[node] = (1.0f - zs) * ht;
}

// ---------------- atomic fallback ----------------

__global__ void k_deg_atomic(const int* __restrict__ srcp, const int* __restrict__ dstp,
                             const float* __restrict__ w, float* __restrict__ deg,
                             long long ne)
{
    const long long ng = (ne + 3) >> 2;
    const long long stride = (long long)gridDim.x * blockDim.x;
    for (long long g = (long long)blockIdx.x * blockDim.x + threadIdx.x; g < ng; g += stride) {
        const long long e = g << 2;
        if (e + 3 < ne) {
            int4 s4 = *(const int4*)(srcp + e);
            int4 d4 = *(const int4*)(dstp + e);
            float4 w4 = *(const float4*)(w + e);
            if (s4.x != d4.x) atomAddF(&deg[s4.x], w4.x);
            if (s4.y != d4.y) atomAddF(&deg[s4.y], w4.y);
            if (s4.z != d4.z) atomAddF(&deg[s4.z], w4.z);
            if (s4.w != d4.w) atomAddF(&deg[s4.w], w4.w);
        } else {
            for (long long q = e; q < ne; ++q) {
                int s = srcp[q], d = dstp[q];
                if (s != d) atomAddF(&deg[s], w[q]);
            }
        }
    }
}

__global__ void k_dinv_inplace(float* __restrict__ deg, int n)
{
    int i = blockIdx.x * blockDim.x + threadIdx.x;
    if (i < n) {
        float d = deg[i];
        deg[i] = (d > 0.0f) ? rsqrtf(d) : 0.0f;
    }
}

__global__ void k_prop_atomic(const int* __restrict__ srcp, const int* __restrict__ dstp,
                              const float* __restrict__ w, const float* __restrict__ dinv,
                              const float2* __restrict__ xin, float* __restrict__ acc,
                              long long ne)
{
    const long long ng = (ne + 3) >> 2;
    const long long stride = (long long)gridDim.x * blockDim.x;
    for (long long g = (long long)blockIdx.x * blockDim.x + threadIdx.x; g < ng; g += stride) {
        const long long e = g << 2;
        if (e + 3 < ne) {
            int4 s4 = *(const int4*)(srcp + e);
            int4 d4 = *(const int4*)(dstp + e);
            float4 w4 = *(const float4*)(w + e);
            int s[4] = {s4.x, s4.y, s4.z, s4.w};
            int d[4] = {d4.x, d4.y, d4.z, d4.w};
            float wv[4] = {w4.x, w4.y, w4.z, w4.w};
#pragma unroll
            for (int j = 0; j < 4; ++j) {
                float wn = (s[j] != d[j]) ? -(dinv[s[j]] * wv[j] * dinv[d[j]]) : 0.0f;
                float2 xv = xin[s[j]];
                atomAddF(&acc[2 * d[j] + 0], wn * xv.x);
                atomAddF(&acc[2 * d[j] + 1], wn * xv.y);
            }
        } else {
            for (long long q = e; q < ne; ++q) {
                int ss = srcp[q], dd = dstp[q];
                float wn = (ss != dd) ? -(dinv[ss] * w[q] * dinv[dd]) : 0.0f;
                float2 xv = xin[ss];
                atomAddF(&acc[2 * dd + 0], wn * xv.x);
                atomAddF(&acc[2 * dd + 1], wn * xv.y);
            }
        }
    }
}

__global__ void k_final(const float2* __restrict__ x, const float2* __restrict__ tx1,
                        const float2* __restrict__ tx2a,
                        const float* __restrict__ Wxz, const float* __restrict__ Wxh,
                        const float* __restrict__ bxz, const float* __restrict__ bhz,
                        const float* __restrict__ bxh, const float* __restrict__ bhh,
                        float* __restrict__ out, int n)
{
    int i = blockIdx.x * blockDim.x + threadIdx.x;
    if (i >= n) return;
    float2 t0 = x[i];
    float2 t1 = tx1[i];
    float2 ta = tx2a[i];
    float t2x = 2.0f * ta.x - t0.x;
    float t2y = 2.0f * ta.y - t0.y;
    float z = t0.x * Wxz[0] + t0.y * Wxz[1]
            + t1.x * Wxz[2] + t1.y * Wxz[3]
            + t2x  * Wxz[4] + t2y  * Wxz[5] + bxz[0] + bhz[0];
    float h = t0.x * Wxh[0] + t0.y * Wxh[1]
            + t1.x * Wxh[2] + t1.y * Wxh[3]
            + t2x  * Wxh[4] + t2y  * Wxh[5] + bxh[0] + bhh[0];
    float zs = 1.0f / (1.0f + expf(-z));
    float ht = tanhf(h);
    out[i] = (1.0f - zs) * ht;
}

// ---------------- launch ----------------

extern "C" void kernel_launch(void* const* d_in, const int* in_sizes, int n_in,
                              void* d_out, int out_size, void* d_ws, size_t ws_size,
                              hipStream_t stream)
{
    const float* x   = (const float*)d_in[0];
    const int*   ei  = (const int*)d_in[1];
    const float* w   = (const float*)d_in[2];
    const float* Wxz = (const float*)d_in[3];
    const float* Wxh = (const float*)d_in[5];
    const float* bxz = (const float*)d_in[9];
    const float* bhz = (const float*)d_in[10];
    const float* bxh = (const float*)d_in[13];
    const float* bhh = (const float*)d_in[14];

    const int n = in_sizes[0] / 2;
    const long long ne = in_sizes[2];
    const int* srcp = ei;
    const int* dstp = ei + ne;
    const int nblocks = (n + BLK - 1) / BLK;
    const int NBC = (n + BSIZE - 1) >> BSHIFT;
    const int NCH = (int)((ne + SCH - 1) / SCH);
    char* ws = (char*)d_ws;

    const bool nodes_ok = (n <= (1 << 19)) && (NBC <= NBC_MAX);
    const int split = 8;

    auto align256 = [](size_t v) { return (v + 255) & ~(size_t)255; };
    const size_t recBytes  = align256((size_t)ne * 8);
    const size_t dinvBytes = align256((size_t)n * 4);
    const size_t vecBytes  = align256((size_t)n * 8);
    const size_t histBytes = align256((size_t)NBC_MAX * 4);
    const size_t partPropBytes = (size_t)NBC * split * BSIZE * 8;
    const size_t partDegBytes  = (size_t)NBC * split * BSIZE * 4;

    size_t off = 0;
    char* pRecA = ws + off; off += recBytes;
    char* pRecB = ws + off; off += recBytes;
    char* pDinv = ws + off; off += dinvBytes;
    char* pY0   = ws + off; off += vecBytes;
    char* pY1   = ws + off; off += vecBytes;
    char* pTx1  = ws + off; off += vecBytes;
    char* pHist = ws + off; off += 6 * histBytes;
    const size_t need_twopass = off;
    const bool twopass = nodes_ok && (need_twopass <= ws_size)
                       && (partPropBytes <= recBytes) && (partDegBytes <= recBytes);

    if (twopass) {
        uint2* recA = (uint2*)pRecA;
        uint2* recB = (uint2*)pRecB;
        float* dinv = (float*)pDinv;
        float2* y0  = (float2*)pY0;
        float2* y1  = (float2*)pY1;
        float2* tx1 = (float2*)pTx1;
        int* histS = (int*)pHist;
        int* histD = (int*)(pHist + histBytes);
        int* baseS = (int*)(pHist + 2 * histBytes);
        int* baseD = (int*)(pHist + 3 * histBytes);
        int* curS  = (int*)(pHist + 4 * histBytes);
        int* curD  = (int*)(pHist + 5 * histBytes);
        float* partDeg  = (float*)pRecB;   // dead until k_sortB writes recB
        float* partProp = (float*)pRecA;   // recA dead after k_sortB

        k_zero_ints<<<(2 * NBC_MAX + BLK - 1) / BLK, BLK, 0, stream>>>(histS, 2 * NBC_MAX);
        k_hist<<<2048, BLK, 0, stream>>>(srcp, dstp, histS, histD, ne, NBC);
        k_scan<<<2, BLK, 0, stream>>>(histS, baseS, curS, histD, baseD, curD, NBC);
        k_sortA<<<NCH, BLK_SS, 0, stream>>>(srcp, dstp, w, curS, recA, ne, NBC, NCH);
        k_degaccA<<<NBC * split, BLK_ACC, 0, stream>>>(recA, baseS, histS, partDeg, split);
        k_degfin<<<nblocks, BLK, 0, stream>>>(partDeg, (const float2*)x, dinv, y0, n, split);
        k_sortB<<<NCH, BLK_SS, 0, stream>>>(recA, baseS, curD, recB, ne, NBC, NCH);
        k_propacc<<<NBC * split, BLK_ACC, 0, stream>>>(recB, baseD, histD, y0,
                                                       (float2*)partProp, split);
        k_propfin1<<<nblocks, BLK, 0, stream>>>((const float2*)partProp, dinv,
                                                tx1, y1, n, split);
        k_propacc<<<NBC * split, BLK_ACC, 0, stream>>>(recB, baseD, histD, y1,
                                                       (float2*)partProp, split);
        k_propfin2<<<nblocks, BLK, 0, stream>>>((const float2*)partProp, dinv,
                                                (const float2*)x, tx1,
                                                Wxz, Wxh, bxz, bhz, bxh, bhh,
                                                (float*)d_out, n, split);
        return;
    }

    // last-resort: global-atomic path
    size_t foff = 0;
    auto falloc = [&](size_t bytes) -> char* {
        char* p = ws + foff;
        foff = (foff + bytes + 255) & ~(size_t)255;
        return p;
    };
    float* deg   = (float*)falloc((size_t)n * sizeof(float));
    float* ftx1  = (float*)falloc((size_t)n * 2 * sizeof(float));
    float* ftx2a = (float*)falloc((size_t)n * 2 * sizeof(float));
    const long long n4 = (long long)(foff / 16);
    k_zero_f4<<<1024, BLK, 0, stream>>>((float4*)ws, n4);
    k_deg_atomic<<<4096, BLK, 0, stream>>>(srcp, dstp, w, deg, ne);
    k_dinv_inplace<<<nblocks, BLK, 0, stream>>>(deg, n);
    k_prop_atomic<<<4096, BLK, 0, stream>>>(srcp, dstp, w, deg,
                                            (const float2*)x, ftx1, ne);
    k_prop_atomic<<<4096, BLK, 0, stream>>>(srcp, dstp, w, deg,
                                            (const float2*)ftx1, ftx2a, ne);
    k_final<<<nblocks, BLK, 0, stream>>>((const float2*)x, (const float2*)ftx1,
                                         (const float2*)ftx2a,
                                         Wxz, Wxh, bxz, bhz, bxh, bhh,
                                         (float*)d_out, n);
}